// Round 1
// baseline (3627.444 us; speedup 1.0000x reference)
//
#include <hip/hip_runtime.h>
#include <cstdint>
#include <cmath>

#define HW 64
#define NPIX 4096          // 64*64
#define CIN 512
#define NANCH 36864        // 4096*9
#define PREN 3000
#define POSTN 300

// ---------------- 3x3 conv + bias + ReLU -> feat2 (NHWC) ----------------
// grid (16 oc-tiles, 64 y, 4 n), block 256. Thread: 1 oc x 8 px, 16-ic chunks.
__global__ __launch_bounds__(256) void conv3_kernel(
    const float* __restrict__ x, const float* __restrict__ w,
    const float* __restrict__ b, float* __restrict__ feat2) {
  const int oct = blockIdx.x;
  const int y   = blockIdx.y;
  const int n   = blockIdx.z;
  const int t   = threadIdx.x;
  const int ocq = t >> 3;          // 0..31
  const int pxg = t & 7;           // 0..7
  const int px0 = pxg << 3;
  const int oc  = (oct << 5) + ocq;

  __shared__ float xs[16*3*68];    // [icl][r][col pad 68], col 0..65 <-> xx-1..64
  __shared__ float wsm[144*33];    // [(icl*9+k)][oc pad 33] : write stride-33 (cf-free), read stride-1

  float acc[8];
#pragma unroll
  for (int j = 0; j < 8; ++j) acc[j] = 0.f;

  const float* xb = x + (size_t)n * CIN * NPIX;
  const float* wb = w + (size_t)(oct << 5) * CIN * 9;

  for (int icc = 0; icc < CIN; icc += 16) {
    for (int idx = t; idx < 16*3*66; idx += 256) {
      int icl = idx / 198;
      int rem = idx - icl*198;
      int r   = rem / 66;
      int col = rem - r*66;
      int yy = y + r - 1;
      int xx = col - 1;
      float v = 0.f;
      if ((unsigned)yy < 64u && (unsigned)xx < 64u)
        v = xb[(size_t)(icc+icl)*NPIX + yy*64 + xx];
      xs[icl*204 + r*68 + col] = v;
    }
    for (int idx = t; idx < 16*9*32; idx += 256) {
      int ocq2 = idx / 144;
      int rem  = idx - ocq2*144;                 // icl*9+k, source-contiguous
      wsm[rem*33 + ocq2] = wb[(size_t)ocq2*CIN*9 + icc*9 + rem];
    }
    __syncthreads();
#pragma unroll 1
    for (int icl = 0; icl < 16; ++icl) {
      float xrf[3][12];
#pragma unroll
      for (int r = 0; r < 3; ++r) {
        const float4* rp = (const float4*)&xs[icl*204 + r*68 + px0];  // 16B-aligned
        float4 a0 = rp[0], a1 = rp[1], a2 = rp[2];
        xrf[r][0]=a0.x; xrf[r][1]=a0.y; xrf[r][2]=a0.z; xrf[r][3]=a0.w;
        xrf[r][4]=a1.x; xrf[r][5]=a1.y; xrf[r][6]=a1.z; xrf[r][7]=a1.w;
        xrf[r][8]=a2.x; xrf[r][9]=a2.y; xrf[r][10]=a2.z; xrf[r][11]=a2.w;
      }
      float wv[9];
#pragma unroll
      for (int k = 0; k < 9; ++k) wv[k] = wsm[(icl*9+k)*33 + ocq];
#pragma unroll
      for (int j = 0; j < 8; ++j) {
        float s = acc[j];
#pragma unroll
        for (int r = 0; r < 3; ++r) {
          s = fmaf(wv[r*3+0], xrf[r][j+0], s);
          s = fmaf(wv[r*3+1], xrf[r][j+1], s);
          s = fmaf(wv[r*3+2], xrf[r][j+2], s);
        }
        acc[j] = s;
      }
    }
    __syncthreads();
  }
  float bias = b[oc];
  float* ob = feat2 + ((size_t)n*NPIX + y*64 + px0) * 512 + oc;
#pragma unroll
  for (int j = 0; j < 8; ++j) {
    float v = acc[j] + bias;
    ob[(size_t)j*512] = v > 0.f ? v : 0.f;   // L2 write-combines the strided b32s
  }
}

// ---------------- 1x1 convs (36 loc + 18 score) + bias -> out0/out1 ------
// grid (64 y, 4 n), block 256: px = t&63, grp = t>>6, ch = grp + 4k
__global__ __launch_bounds__(256) void conv1_kernel(
    const float* __restrict__ feat2,
    const float* __restrict__ w_loc, const float* __restrict__ b_loc,
    const float* __restrict__ w_score, const float* __restrict__ b_score,
    float* __restrict__ out_locs, float* __restrict__ out_scores) {
  const int y = blockIdx.x, n = blockIdx.y;
  const int t = threadIdx.x;
  const int px = t & 63, grp = t >> 6;
  __shared__ float fl[64*129];     // [px][ic pad 129] -> bank stride 1, 2-way max
  __shared__ float wl[54*128];     // [c][ic] -> wave-uniform broadcast reads
  float acc[14];
#pragma unroll
  for (int k = 0; k < 14; ++k) acc[k] = 0.f;
  const float* fb = feat2 + ((size_t)n*NPIX + y*64) * 512;
  for (int ch = 0; ch < 512; ch += 128) {
    for (int idx = t; idx < 64*128; idx += 256) {
      int p = idx >> 7, ic = idx & 127;
      fl[p*129 + ic] = fb[(size_t)p*512 + ch + ic];
    }
    for (int idx = t; idx < 54*128; idx += 256) {
      int c = idx >> 7, ic = idx & 127;
      wl[c*128 + ic] = (c < 36) ? w_loc[c*512 + ch + ic]
                                : w_score[(c-36)*512 + ch + ic];
    }
    __syncthreads();
#pragma unroll 1
    for (int ic = 0; ic < 128; ++ic) {
      float f = fl[px*129 + ic];
#pragma unroll
      for (int k = 0; k < 14; ++k) {
        int c = grp + 4*k;
        if (c < 54) acc[k] = fmaf(wl[c*128 + ic], f, acc[k]);
      }
    }
    __syncthreads();
  }
  size_t pix = (size_t)y*64 + px;
#pragma unroll
  for (int k = 0; k < 14; ++k) {
    int c = grp + 4*k;
    if (c < 36) {
      out_locs[((size_t)n*NPIX + pix)*36 + c] = acc[k] + b_loc[c];
    } else if (c < 54) {
      out_scores[((size_t)n*NPIX + pix)*18 + (c-36)] = acc[k] + b_score[c-36];
    }
  }
}

// ------------- anchors (f64->f32 like numpy) + decode + softmax + keys ----
__global__ __launch_bounds__(256) void decode_kernel(
    const float* __restrict__ locs, const float* __restrict__ scores,
    const int* __restrict__ ih, const int* __restrict__ iw,
    float* __restrict__ boxes, unsigned* __restrict__ keys,
    float* __restrict__ out_anchor) {
#pragma clang fp contract(off)
  int gid = blockIdx.x*256 + threadIdx.x;
  if (gid >= 4*NANCH) return;
  int n = gid / NANCH;
  int i = gid - n*NANCH;
  int a = i % 9;
  int pix = i / 9;
  int xq = pix & 63, yq = pix >> 6;
  int ri = a / 3, si = a - ri*3;
  double ratio = (ri == 0) ? 0.5 : (ri == 1 ? 1.0 : 2.0);
  double scl   = (si == 0) ? 8.0 : (si == 1 ? 16.0 : 32.0);
  double hh = 16.0 * scl * sqrt(ratio);
  double ww = 16.0 * scl * sqrt(1.0 / ratio);
  float sx = (float)(xq * 16), sy = (float)(yq * 16);
  float ax1 = (float)(8.0 - ww*0.5) + sx;
  float ay1 = (float)(8.0 - hh*0.5) + sy;
  float ax2 = (float)(8.0 + ww*0.5) + sx;
  float ay2 = (float)(8.0 + hh*0.5) + sy;
  if (n == 0) {
    *(float4*)(out_anchor + (size_t)i*4) = make_float4(ax1, ay1, ax2, ay2);
  }
  const float* lp = locs + ((size_t)n*NPIX + pix)*36 + a*4;
  float l0 = lp[0], l1 = lp[1], l2 = lp[2], l3 = lp[3];
  float aw = ax2 - ax1, ah = ay2 - ay1;
  float cx = ax1 + 0.5f*aw, cy = ay1 + 0.5f*ah;
  float ctrx = l0*aw + cx, ctry = l1*ah + cy;
  float nw = expf(l2)*aw, nh = expf(l3)*ah;
  float x1 = ctrx - 0.5f*nw, y1 = ctry - 0.5f*nh;
  float x2 = ctrx + 0.5f*nw, y2 = ctry + 0.5f*nh;
  float W = (float)iw[0], H = (float)ih[0];
  x1 = fminf(fmaxf(x1, 0.f), W);
  y1 = fminf(fmaxf(y1, 0.f), H);
  x2 = fminf(fmaxf(x2, 0.f), W);
  y2 = fminf(fmaxf(y2, 0.f), H);
  bool valid = ((x2 - x1) >= 16.f) && ((y2 - y1) >= 16.f);
  const float* sp = scores + ((size_t)n*NPIX + pix)*18 + a*2;
  float s0 = sp[0], s1 = sp[1];
  float mx = fmaxf(s0, s1);
  float e0 = expf(s0-mx), e1 = expf(s1-mx);
  float fg = e1/(e0+e1);
  float sc = valid ? fg : -1e9f;
  unsigned bb = __float_as_uint(sc);
  unsigned u = (bb & 0x80000000u) ? ~bb : (bb | 0x80000000u);  // ascending map
  keys[gid] = u;
  *(float4*)(boxes + (size_t)gid*4) = make_float4(x1, y1, x2, y2);
}

// -------- exact stable top-3000 by rank counting (u64 total-order key) ----
__global__ __launch_bounds__(256) void rank_kernel(
    const unsigned* __restrict__ keys, const float* __restrict__ boxes,
    float* __restrict__ sboxes) {
  int n = blockIdx.y;
  int i = blockIdx.x*256 + threadIdx.x;
  const unsigned* kb = keys + (size_t)n*NANCH;
  unsigned long long Ki = ((unsigned long long)(~kb[i]) << 32) | (unsigned)i;
  __shared__ unsigned long long tile[256];
  int rank = 0;
  for (int t0 = 0; t0 < NANCH; t0 += 256) {
    __syncthreads();
    tile[threadIdx.x] =
        ((unsigned long long)(~kb[t0 + threadIdx.x]) << 32) | (unsigned)(t0 + threadIdx.x);
    __syncthreads();
#pragma unroll 16
    for (int jj = 0; jj < 256; ++jj)
      rank += (tile[jj] < Ki) ? 1 : 0;   // j before i in (score desc, idx asc)
  }
  if (rank < PREN) {
    float4 bb = *(const float4*)(boxes + ((size_t)n*NANCH + i)*4);
    *(float4*)(sboxes + ((size_t)n*PREN + rank)*4) = bb;
  }
}

// ------------------ suppression bit-matrix (IoU > 0.7) --------------------
__global__ __launch_bounds__(256) void iou_kernel(
    const float* __restrict__ sboxes, unsigned long long* __restrict__ sup) {
#pragma clang fp contract(off)
  int n = blockIdx.y, i = blockIdx.x;
  const float* B = sboxes + (size_t)n*PREN*4;
  float4 bi = *(const float4*)(B + (size_t)i*4);
  float area_i = (bi.z - bi.x) * (bi.w - bi.y);
  int lane = threadIdx.x & 63, wv = threadIdx.x >> 6;
  unsigned long long* row = sup + ((size_t)n*PREN + i)*64;
  for (int w0 = wv; w0 < 64; w0 += 4) {
    int j = w0*64 + lane;
    bool p = false;
    if (j < PREN) {
      float4 bj = *(const float4*)(B + (size_t)j*4);
      float area_j = (bj.z - bj.x) * (bj.w - bj.y);
      float x1 = fmaxf(bi.x, bj.x), y1 = fmaxf(bi.y, bj.y);
      float x2 = fminf(bi.z, bj.z), y2 = fminf(bi.w, bj.w);
      float inter = fmaxf(x2 - x1, 0.f) * fmaxf(y2 - y1, 0.f);
      float iou = inter / (area_i + area_j - inter + 1e-9f);
      p = iou > 0.7f;
    }
    unsigned long long m = __ballot(p);
    if (lane == 0) row[w0] = m;
  }
}

// -------- sequential greedy sweep (1 wave/image) + emit 300 rois ----------
__global__ __launch_bounds__(64) void nms_kernel(
    const unsigned long long* __restrict__ sup, const float* __restrict__ sboxes,
    float* __restrict__ rois, float* __restrict__ ridx) {
  int n = blockIdx.x;
  int lane = threadIdx.x;
  const unsigned long long* S = sup + (size_t)n*PREN*64;
  unsigned long long buf[8];
#pragma unroll
  for (int k = 0; k < 8; ++k) buf[k] = S[(size_t)k*64 + lane];
  unsigned long long keep = (lane < 46) ? ~0ull
                          : (lane == 46 ? ((1ull << 56) - 1ull) : 0ull); // 3000 bits
  for (int i0 = 0; i0 < PREN; i0 += 8) {
#pragma unroll
    for (int k = 0; k < 8; ++k) {
      const int i = i0 + k;
      unsigned long long r = buf[k];
      if (i + 8 < PREN) buf[k] = S[(size_t)(i+8)*64 + lane];   // prefetch
      const int wqi = i >> 6, bqi = i & 63;
      unsigned long long kw = __shfl(keep, wqi);
      if ((kw >> bqi) & 1ull) {        // i survives -> suppress its overlaps j>i
        unsigned long long m;
        if (lane < wqi) m = 0ull;
        else if (lane > wqi) m = ~0ull;
        else m = (bqi == 63) ? 0ull : ~((1ull << (bqi+1)) - 1ull);
        keep &= ~(r & m);
      }
    }
  }
  int cnt = __popcll(keep);
  int scn = cnt;
  for (int d = 1; d < 64; d <<= 1) {
    int v = __shfl_up(scn, d);
    if (lane >= d) scn += v;
  }
  int excl = scn - cnt;
  int total = __shfl(scn, 63);
  const float* SB = sboxes + (size_t)n*PREN*4;
  unsigned long long kk = keep;
  int p = excl;
  while (kk) {
    int bpos = __ffsll(kk) - 1;
    kk &= kk - 1ull;
    if (p < POSTN) {
      float4 bb = *(const float4*)(SB + (size_t)(lane*64 + bpos)*4);
      *(float4*)(rois + ((size_t)n*POSTN + p)*4) = bb;
    }
    ++p;
  }
  if (lane == 0) {                        // pad with box 0 (always kept)
    float4 b0 = *(const float4*)SB;
    for (int q = total; q < POSTN; ++q)
      *(float4*)(rois + ((size_t)n*POSTN + q)*4) = b0;
  }
  for (int q = lane; q < POSTN; q += 64) ridx[n*POSTN + q] = (float)n;
}

extern "C" void kernel_launch(void* const* d_in, const int* in_sizes, int n_in,
                              void* d_out, int out_size, void* d_ws, size_t ws_size,
                              hipStream_t stream) {
  const float* x       = (const float*)d_in[0];
  const float* w_conv  = (const float*)d_in[1];
  const float* b_conv  = (const float*)d_in[2];
  const float* w_score = (const float*)d_in[3];
  const float* b_score = (const float*)d_in[4];
  const float* w_loc   = (const float*)d_in[5];
  const float* b_loc   = (const float*)d_in[6];
  const int*   img_h   = (const int*)d_in[7];
  const int*   img_w   = (const int*)d_in[8];

  float* out        = (float*)d_out;
  float* out_locs   = out;                 // (4,36864,4)  589824
  float* out_scores = out + 589824;        // (4,36864,2)  294912
  float* out_rois   = out + 884736;        // (4,300,4)      4800
  float* out_ridx   = out + 889536;        // (4,300)        1200
  float* out_anchor = out + 890736;        // (1,36864,4)  147456

  float* feat2  = (float*)d_ws;                          // 33.5 MB NHWC feat
  float* boxes  = feat2 + (size_t)8388608;               // 4*36864*4 f32
  unsigned* keys = (unsigned*)(boxes + 589824);          // 4*36864 u32
  float* sboxes = (float*)(keys + 147456);               // 4*3000*4 f32
  unsigned long long* sup = (unsigned long long*)(sboxes + 48000); // 4*3000*64 u64

  conv3_kernel<<<dim3(16, 64, 4), 256, 0, stream>>>(x, w_conv, b_conv, feat2);
  conv1_kernel<<<dim3(64, 4), 256, 0, stream>>>(feat2, w_loc, b_loc,
                                                w_score, b_score, out_locs, out_scores);
  decode_kernel<<<576, 256, 0, stream>>>(out_locs, out_scores, img_h, img_w,
                                         boxes, keys, out_anchor);
  rank_kernel<<<dim3(144, 4), 256, 0, stream>>>(keys, boxes, sboxes);
  iou_kernel<<<dim3(PREN, 4), 256, 0, stream>>>(sboxes, sup);
  nms_kernel<<<4, 64, 0, stream>>>(sup, sboxes, out_rois, out_ridx);
}

// Round 2
// 2828.150 us; speedup vs baseline: 1.2826x; 1.2826x over previous
//
#include <hip/hip_runtime.h>
#include <cstdint>
#include <cmath>

#define HW 64
#define NPIX 4096          // 64*64
#define CIN 512
#define NANCH 36864        // 4096*9
#define PREN 3000
#define POSTN 300
#define ICL 16

// ---------------- W reshape: w[oc][ic][3][3] -> w2[g1][ic][k][o8] ---------
// g1 = oct*4 + wid (64 groups of 8 oc), oc = (g1>>2)*32 + (g1&3)*8 + o8
__global__ __launch_bounds__(256) void reshape_w_kernel(
    const float* __restrict__ w, float* __restrict__ w2) {
  int gid = blockIdx.x * 256 + threadIdx.x;
  if (gid >= 512 * 512 * 9) return;
  int o8  = gid & 7;
  int rem = gid >> 3;          // (g1*512 + ic)*9 + k
  int k   = rem % 9;
  int rem2 = rem / 9;          // g1*512 + ic
  int ic  = rem2 & 511;
  int g1  = rem2 >> 9;
  int oc  = (g1 >> 2) * 32 + (g1 & 3) * 8 + o8;
  w2[gid] = w[((size_t)oc * 512 + ic) * 9 + k];
}

// ---------------- 3x3 conv + bias + ReLU -> feat2 (NHWC) -----------------
// grid (16 oct, 16 ytile, 4 n), block 256 = 4 waves.
// Wave = 8 oc (wave-uniform -> W via s_load), lane = 4 px (16 lanes/row x 4 rows).
__global__ __launch_bounds__(256) void conv3_kernel(
    const float* __restrict__ x, const float* __restrict__ w2,
    const float* __restrict__ b, float* __restrict__ feat2) {
  const int oct = blockIdx.x;      // 0..15
  const int yt  = blockIdx.y;      // 0..15
  const int n   = blockIdx.z;
  const int t   = threadIdx.x;
  const int wid  = __builtin_amdgcn_readfirstlane(t >> 6);  // wave-uniform
  const int lane = t & 63;
  const int lrow = lane >> 4;          // 0..3
  const int lcol = (lane & 15) << 2;   // 0..60
  const int y0 = yt << 2;

  __shared__ float xs[ICL * 6 * 68];   // [icl][row 6][col pad 68], col c <-> xx=c-1

  float acc[8][4];
#pragma unroll
  for (int o = 0; o < 8; ++o)
#pragma unroll
    for (int j = 0; j < 4; ++j) acc[o][j] = 0.f;

  const float* xb = x + (size_t)n * CIN * NPIX;
  const float* __restrict__ wq = w2 + (size_t)(oct * 4 + wid) * (512 * 72);

  for (int icc = 0; icc < CIN; icc += ICL) {
    __syncthreads();
    for (int s = t; s < ICL * 6 * 66; s += 256) {
      int icl = s / 396;
      int rem = s - icl * 396;
      int row = rem / 66;
      int c   = rem - row * 66;
      int yy = y0 - 1 + row;
      int xx = c - 1;
      float v = 0.f;
      if ((unsigned)yy < 64u && (unsigned)xx < 64u)
        v = xb[(size_t)(icc + icl) * NPIX + yy * 64 + xx];
      xs[icl * 408 + row * 68 + c] = v;
    }
    __syncthreads();
#pragma unroll 1
    for (int icl = 0; icl < ICL; ++icl) {
      const float* __restrict__ wp = wq + (size_t)(icc + icl) * 72;  // uniform -> s_load
      const float* xp = &xs[icl * 408 + lrow * 68 + lcol];
      float4 a0 = *(const float4*)(xp);
      float2 b0 = *(const float2*)(xp + 4);
      float4 a1 = *(const float4*)(xp + 68);
      float2 b1 = *(const float2*)(xp + 72);
      float4 a2 = *(const float4*)(xp + 136);
      float2 b2 = *(const float2*)(xp + 140);
      float xr[3][6] = {{a0.x, a0.y, a0.z, a0.w, b0.x, b0.y},
                        {a1.x, a1.y, a1.z, a1.w, b1.x, b1.y},
                        {a2.x, a2.y, a2.z, a2.w, b2.x, b2.y}};
#pragma unroll
      for (int r = 0; r < 3; ++r)
#pragma unroll
        for (int kx = 0; kx < 3; ++kx) {
          const int tap = r * 3 + kx;
#pragma unroll
          for (int o = 0; o < 8; ++o) {
            float wv = wp[tap * 8 + o];      // SGPR broadcast
#pragma unroll
            for (int j = 0; j < 4; ++j)
              acc[o][j] = fmaf(wv, xr[r][j + kx], acc[o][j]);
          }
        }
    }
  }
  const float* __restrict__ bs = b + oct * 32 + wid * 8;  // uniform
  float bias[8];
#pragma unroll
  for (int o = 0; o < 8; ++o) bias[o] = bs[o];
  float* ob = feat2 + ((size_t)n * NPIX + (y0 + lrow) * 64 + lcol) * 512 + oct * 32 + wid * 8;
#pragma unroll
  for (int j = 0; j < 4; ++j) {
    float4 v0, v1;
    v0.x = fmaxf(acc[0][j] + bias[0], 0.f);
    v0.y = fmaxf(acc[1][j] + bias[1], 0.f);
    v0.z = fmaxf(acc[2][j] + bias[2], 0.f);
    v0.w = fmaxf(acc[3][j] + bias[3], 0.f);
    v1.x = fmaxf(acc[4][j] + bias[4], 0.f);
    v1.y = fmaxf(acc[5][j] + bias[5], 0.f);
    v1.z = fmaxf(acc[6][j] + bias[6], 0.f);
    v1.w = fmaxf(acc[7][j] + bias[7], 0.f);
    *(float4*)(ob + (size_t)j * 512)     = v0;
    *(float4*)(ob + (size_t)j * 512 + 4) = v1;
  }
}

// ---------------- 1x1 convs (36 loc + 18 score) + bias -> out0/out1 ------
__global__ __launch_bounds__(256) void conv1_kernel(
    const float* __restrict__ feat2,
    const float* __restrict__ w_loc, const float* __restrict__ b_loc,
    const float* __restrict__ w_score, const float* __restrict__ b_score,
    float* __restrict__ out_locs, float* __restrict__ out_scores) {
  const int y = blockIdx.x, n = blockIdx.y;
  const int t = threadIdx.x;
  const int px = t & 63, grp = t >> 6;
  __shared__ float fl[64 * 129];
  __shared__ float wl[54 * 128];
  float acc[14];
#pragma unroll
  for (int k = 0; k < 14; ++k) acc[k] = 0.f;
  const float* fb = feat2 + ((size_t)n * NPIX + y * 64) * 512;
  for (int ch = 0; ch < 512; ch += 128) {
    for (int idx = t; idx < 64 * 128; idx += 256) {
      int p = idx >> 7, ic = idx & 127;
      fl[p * 129 + ic] = fb[(size_t)p * 512 + ch + ic];
    }
    for (int idx = t; idx < 54 * 128; idx += 256) {
      int c = idx >> 7, ic = idx & 127;
      wl[c * 128 + ic] = (c < 36) ? w_loc[c * 512 + ch + ic]
                                  : w_score[(c - 36) * 512 + ch + ic];
    }
    __syncthreads();
#pragma unroll 1
    for (int ic = 0; ic < 128; ++ic) {
      float f = fl[px * 129 + ic];
#pragma unroll
      for (int k = 0; k < 14; ++k) {
        int c = grp + 4 * k;
        if (c < 54) acc[k] = fmaf(wl[c * 128 + ic], f, acc[k]);
      }
    }
    __syncthreads();
  }
  size_t pix = (size_t)y * 64 + px;
#pragma unroll
  for (int k = 0; k < 14; ++k) {
    int c = grp + 4 * k;
    if (c < 36) {
      out_locs[((size_t)n * NPIX + pix) * 36 + c] = acc[k] + b_loc[c];
    } else if (c < 54) {
      out_scores[((size_t)n * NPIX + pix) * 18 + (c - 36)] = acc[k] + b_score[c - 36];
    }
  }
}

// ------------- anchors (f64->f32 like numpy) + decode + softmax + keys ----
__global__ __launch_bounds__(256) void decode_kernel(
    const float* __restrict__ locs, const float* __restrict__ scores,
    const int* __restrict__ ih, const int* __restrict__ iw,
    float* __restrict__ boxes, unsigned* __restrict__ keys,
    float* __restrict__ out_anchor) {
#pragma clang fp contract(off)
  int gid = blockIdx.x * 256 + threadIdx.x;
  if (gid >= 4 * NANCH) return;
  int n = gid / NANCH;
  int i = gid - n * NANCH;
  int a = i % 9;
  int pix = i / 9;
  int xq = pix & 63, yq = pix >> 6;
  int ri = a / 3, si = a - ri * 3;
  double ratio = (ri == 0) ? 0.5 : (ri == 1 ? 1.0 : 2.0);
  double scl   = (si == 0) ? 8.0 : (si == 1 ? 16.0 : 32.0);
  double hh = 16.0 * scl * sqrt(ratio);
  double ww = 16.0 * scl * sqrt(1.0 / ratio);
  float sx = (float)(xq * 16), sy = (float)(yq * 16);
  float ax1 = (float)(8.0 - ww * 0.5) + sx;
  float ay1 = (float)(8.0 - hh * 0.5) + sy;
  float ax2 = (float)(8.0 + ww * 0.5) + sx;
  float ay2 = (float)(8.0 + hh * 0.5) + sy;
  if (n == 0) {
    *(float4*)(out_anchor + (size_t)i * 4) = make_float4(ax1, ay1, ax2, ay2);
  }
  const float* lp = locs + ((size_t)n * NPIX + pix) * 36 + a * 4;
  float l0 = lp[0], l1 = lp[1], l2 = lp[2], l3 = lp[3];
  float aw = ax2 - ax1, ah = ay2 - ay1;
  float cx = ax1 + 0.5f * aw, cy = ay1 + 0.5f * ah;
  float ctrx = l0 * aw + cx, ctry = l1 * ah + cy;
  float nw = expf(l2) * aw, nh = expf(l3) * ah;
  float x1 = ctrx - 0.5f * nw, y1 = ctry - 0.5f * nh;
  float x2 = ctrx + 0.5f * nw, y2 = ctry + 0.5f * nh;
  float W = (float)iw[0], H = (float)ih[0];
  x1 = fminf(fmaxf(x1, 0.f), W);
  y1 = fminf(fmaxf(y1, 0.f), H);
  x2 = fminf(fmaxf(x2, 0.f), W);
  y2 = fminf(fmaxf(y2, 0.f), H);
  bool valid = ((x2 - x1) >= 16.f) && ((y2 - y1) >= 16.f);
  const float* sp = scores + ((size_t)n * NPIX + pix) * 18 + a * 2;
  float s0 = sp[0], s1 = sp[1];
  float mx = fmaxf(s0, s1);
  float e0 = expf(s0 - mx), e1 = expf(s1 - mx);
  float fg = e1 / (e0 + e1);
  float sc = valid ? fg : -1e9f;
  unsigned bb = __float_as_uint(sc);
  unsigned u = (bb & 0x80000000u) ? ~bb : (bb | 0x80000000u);  // ascending map
  keys[gid] = u;
  *(float4*)(boxes + (size_t)gid * 4) = make_float4(x1, y1, x2, y2);
}

// -------- exact stable top-3000 by rank counting (u64 total-order key) ----
__global__ __launch_bounds__(256) void rank_kernel(
    const unsigned* __restrict__ keys, const float* __restrict__ boxes,
    float* __restrict__ sboxes) {
  int n = blockIdx.y;
  int i = blockIdx.x * 256 + threadIdx.x;
  const unsigned* kb = keys + (size_t)n * NANCH;
  unsigned long long Ki = ((unsigned long long)(~kb[i]) << 32) | (unsigned)i;
  __shared__ unsigned long long tile[256];
  int rank = 0;
  for (int t0 = 0; t0 < NANCH; t0 += 256) {
    __syncthreads();
    tile[threadIdx.x] =
        ((unsigned long long)(~kb[t0 + threadIdx.x]) << 32) | (unsigned)(t0 + threadIdx.x);
    __syncthreads();
#pragma unroll 16
    for (int jj = 0; jj < 256; ++jj)
      rank += (tile[jj] < Ki) ? 1 : 0;
  }
  if (rank < PREN) {
    float4 bb = *(const float4*)(boxes + ((size_t)n * NANCH + i) * 4);
    *(float4*)(sboxes + ((size_t)n * PREN + rank) * 4) = bb;
  }
}

// ------------------ suppression bit-matrix (IoU > 0.7) --------------------
__global__ __launch_bounds__(256) void iou_kernel(
    const float* __restrict__ sboxes, unsigned long long* __restrict__ sup) {
#pragma clang fp contract(off)
  int n = blockIdx.y, i = blockIdx.x;
  const float* B = sboxes + (size_t)n * PREN * 4;
  float4 bi = *(const float4*)(B + (size_t)i * 4);
  float area_i = (bi.z - bi.x) * (bi.w - bi.y);
  int lane = threadIdx.x & 63, wv = threadIdx.x >> 6;
  unsigned long long* row = sup + ((size_t)n * PREN + i) * 64;
  for (int w0 = wv; w0 < 64; w0 += 4) {
    int j = w0 * 64 + lane;
    bool p = false;
    if (j < PREN) {
      float4 bj = *(const float4*)(B + (size_t)j * 4);
      float area_j = (bj.z - bj.x) * (bj.w - bj.y);
      float x1 = fmaxf(bi.x, bj.x), y1 = fmaxf(bi.y, bj.y);
      float x2 = fminf(bi.z, bj.z), y2 = fminf(bi.w, bj.w);
      float inter = fmaxf(x2 - x1, 0.f) * fmaxf(y2 - y1, 0.f);
      float iou = inter / (area_i + area_j - inter + 1e-9f);
      p = iou > 0.7f;
    }
    unsigned long long m = __ballot(p);
    if (lane == 0) row[w0] = m;
  }
}

// -------- sequential greedy sweep (1 wave/image) + emit 300 rois ----------
__global__ __launch_bounds__(64) void nms_kernel(
    const unsigned long long* __restrict__ sup, const float* __restrict__ sboxes,
    float* __restrict__ rois, float* __restrict__ ridx) {
  int n = blockIdx.x;
  int lane = threadIdx.x;
  const unsigned long long* S = sup + (size_t)n * PREN * 64;
  unsigned long long buf[8];
#pragma unroll
  for (int k = 0; k < 8; ++k) buf[k] = S[(size_t)k * 64 + lane];
  unsigned long long keep = (lane < 46) ? ~0ull
                          : (lane == 46 ? ((1ull << 56) - 1ull) : 0ull);
  for (int i0 = 0; i0 < PREN; i0 += 8) {
#pragma unroll
    for (int k = 0; k < 8; ++k) {
      const int i = i0 + k;
      unsigned long long r = buf[k];
      if (i + 8 < PREN) buf[k] = S[(size_t)(i + 8) * 64 + lane];
      const int wqi = i >> 6, bqi = i & 63;
      unsigned long long kw = __shfl(keep, wqi);
      if ((kw >> bqi) & 1ull) {
        unsigned long long m;
        if (lane < wqi) m = 0ull;
        else if (lane > wqi) m = ~0ull;
        else m = (bqi == 63) ? 0ull : ~((1ull << (bqi + 1)) - 1ull);
        keep &= ~(r & m);
      }
    }
  }
  int cnt = __popcll(keep);
  int scn = cnt;
  for (int d = 1; d < 64; d <<= 1) {
    int v = __shfl_up(scn, d);
    if (lane >= d) scn += v;
  }
  int excl = scn - cnt;
  int total = __shfl(scn, 63);
  const float* SB = sboxes + (size_t)n * PREN * 4;
  unsigned long long kk = keep;
  int p = excl;
  while (kk) {
    int bpos = __ffsll(kk) - 1;
    kk &= kk - 1ull;
    if (p < POSTN) {
      float4 bb = *(const float4*)(SB + (size_t)(lane * 64 + bpos) * 4);
      *(float4*)(rois + ((size_t)n * POSTN + p) * 4) = bb;
    }
    ++p;
  }
  if (lane == 0) {
    float4 b0 = *(const float4*)SB;
    for (int q = total; q < POSTN; ++q)
      *(float4*)(rois + ((size_t)n * POSTN + q) * 4) = b0;
  }
  for (int q = lane; q < POSTN; q += 64) ridx[n * POSTN + q] = (float)n;
}

extern "C" void kernel_launch(void* const* d_in, const int* in_sizes, int n_in,
                              void* d_out, int out_size, void* d_ws, size_t ws_size,
                              hipStream_t stream) {
  const float* x       = (const float*)d_in[0];
  const float* w_conv  = (const float*)d_in[1];
  const float* b_conv  = (const float*)d_in[2];
  const float* w_score = (const float*)d_in[3];
  const float* b_score = (const float*)d_in[4];
  const float* w_loc   = (const float*)d_in[5];
  const float* b_loc   = (const float*)d_in[6];
  const int*   img_h   = (const int*)d_in[7];
  const int*   img_w   = (const int*)d_in[8];

  float* out        = (float*)d_out;
  float* out_locs   = out;                 // (4,36864,4)  589824
  float* out_scores = out + 589824;        // (4,36864,2)  294912
  float* out_rois   = out + 884736;        // (4,300,4)      4800
  float* out_ridx   = out + 889536;        // (4,300)        1200
  float* out_anchor = out + 890736;        // (1,36864,4)  147456

  // workspace: feat2 (33.5 MB) | region A: w2 (9.44 MB, dead after conv3)
  //            aliased by boxes/keys/sboxes/sup (9.26 MB, born at decode)
  float* feat2 = (float*)d_ws;                           // 8388608 f32
  float* A     = feat2 + (size_t)8388608;
  float* w2    = A;                                      // 2359296 f32
  float* boxes = A;                                      // 4*36864*4 f32
  unsigned* keys = (unsigned*)(boxes + 589824);          // 4*36864 u32
  float* sboxes = (float*)(keys + 147456);               // 4*3000*4 f32
  unsigned long long* sup = (unsigned long long*)(sboxes + 48000); // 4*3000*64 u64

  reshape_w_kernel<<<9216, 256, 0, stream>>>(w_conv, w2);
  conv3_kernel<<<dim3(16, 16, 4), 256, 0, stream>>>(x, w2, b_conv, feat2);
  conv1_kernel<<<dim3(64, 4), 256, 0, stream>>>(feat2, w_loc, b_loc,
                                                w_score, b_score, out_locs, out_scores);
  decode_kernel<<<576, 256, 0, stream>>>(out_locs, out_scores, img_h, img_w,
                                         boxes, keys, out_anchor);
  rank_kernel<<<dim3(144, 4), 256, 0, stream>>>(keys, boxes, sboxes);
  iou_kernel<<<dim3(PREN, 4), 256, 0, stream>>>(sboxes, sup);
  nms_kernel<<<4, 64, 0, stream>>>(sup, sboxes, out_rois, out_ridx);
}

// Round 3
// 2286.360 us; speedup vs baseline: 1.5866x; 1.2370x over previous
//
#include <hip/hip_runtime.h>
#include <cstdint>
#include <cmath>

#define HW 64
#define NPIX 4096          // 64*64
#define CIN 512
#define NANCH 36864        // 4096*9
#define PREN 3000
#define POSTN 300
#define ICL 8

// ---------------- W reshape: w[oc][ic][3][3] -> w2[g1][ic][k][o8] ---------
// g1 = oct*4 + wid (64 groups of 8 oc), oc = (g1>>2)*32 + (g1&3)*8 + o8
__global__ __launch_bounds__(256) void reshape_w_kernel(
    const float* __restrict__ w, float* __restrict__ w2) {
  int gid = blockIdx.x * 256 + threadIdx.x;
  if (gid >= 512 * 512 * 9) return;
  int o8  = gid & 7;
  int rem = gid >> 3;          // (g1*512 + ic)*9 + k
  int k   = rem % 9;
  int rem2 = rem / 9;          // g1*512 + ic
  int ic  = rem2 & 511;
  int g1  = rem2 >> 9;
  int oc  = (g1 >> 2) * 32 + (g1 & 3) * 8 + o8;
  w2[gid] = w[((size_t)oc * 512 + ic) * 9 + k];
}

// ---------------- 3x3 conv + bias + ReLU -> feat2 (NHWC) -----------------
// grid (16 oct, 16 ytile, 4 n), block 256 = 4 waves.
// Wave = 8 oc; weights staged in LDS, read as wave-uniform b128 broadcasts.
// Lane = 4 px (16 lanes/row x 4 rows).
__global__ __launch_bounds__(256) void conv3_kernel(
    const float* __restrict__ x, const float* __restrict__ w2,
    const float* __restrict__ b, float* __restrict__ feat2) {
  const int oct = blockIdx.x;      // 0..15
  const int yt  = blockIdx.y;      // 0..15
  const int n   = blockIdx.z;
  const int t   = threadIdx.x;
  const int wid  = __builtin_amdgcn_readfirstlane(t >> 6);  // wave-uniform
  const int lane = t & 63;
  const int lrow = lane >> 4;          // 0..3
  const int lcol = (lane & 15) << 2;   // 0..60
  const int y0 = yt << 2;

  __shared__ float xs[ICL * 6 * 68];   // [icl][row 6][col pad 68], col c <-> xx=c-1
  __shared__ float wsm[4 * ICL * 72];  // [wid][icl][tap 9][o8]

  float acc[8][4];
#pragma unroll
  for (int o = 0; o < 8; ++o)
#pragma unroll
    for (int j = 0; j < 4; ++j) acc[o][j] = 0.f;

  const float* xb = x + (size_t)n * CIN * NPIX;
  const float* __restrict__ wgb = w2 + (size_t)(oct * 4) * (512 * 72);

  for (int icc = 0; icc < CIN; icc += ICL) {
    __syncthreads();
    for (int s = t; s < ICL * 6 * 66; s += 256) {
      int icl = s / 396;
      int rem = s - icl * 396;
      int row = rem / 66;
      int c   = rem - row * 66;
      int yy = y0 - 1 + row;
      int xx = c - 1;
      float v = 0.f;
      if ((unsigned)yy < 64u && (unsigned)xx < 64u)
        v = xb[(size_t)(icc + icl) * NPIX + yy * 64 + xx];
      xs[icl * 408 + row * 68 + c] = v;
    }
    for (int s = t; s < 4 * ICL * 72; s += 256) {
      int w4  = s / (ICL * 72);
      int rem = s - w4 * (ICL * 72);          // icl*72 + j, source-contiguous
      wsm[s] = wgb[(size_t)w4 * (512 * 72) + icc * 72 + rem];
    }
    __syncthreads();
#pragma unroll 1
    for (int icl = 0; icl < ICL; ++icl) {
      const float* xp = &xs[icl * 408 + lrow * 68 + lcol];
      float4 a0 = *(const float4*)(xp);
      float2 b0 = *(const float2*)(xp + 4);
      float4 a1 = *(const float4*)(xp + 68);
      float2 b1 = *(const float2*)(xp + 72);
      float4 a2 = *(const float4*)(xp + 136);
      float2 b2 = *(const float2*)(xp + 140);
      float xr[3][6] = {{a0.x, a0.y, a0.z, a0.w, b0.x, b0.y},
                        {a1.x, a1.y, a1.z, a1.w, b1.x, b1.y},
                        {a2.x, a2.y, a2.z, a2.w, b2.x, b2.y}};
      const float* wp = &wsm[wid * (ICL * 72) + icl * 72];   // uniform -> broadcast
#pragma unroll
      for (int r = 0; r < 3; ++r)
#pragma unroll
        for (int kx = 0; kx < 3; ++kx) {
          const int tap = r * 3 + kx;
          float4 wa = *(const float4*)(wp + tap * 8);
          float4 wb = *(const float4*)(wp + tap * 8 + 4);
          float wv8[8] = {wa.x, wa.y, wa.z, wa.w, wb.x, wb.y, wb.z, wb.w};
#pragma unroll
          for (int o = 0; o < 8; ++o)
#pragma unroll
            for (int j = 0; j < 4; ++j)
              acc[o][j] = fmaf(wv8[o], xr[r][j + kx], acc[o][j]);
        }
    }
  }
  const float* __restrict__ bs = b + oct * 32 + wid * 8;  // uniform
  float bias[8];
#pragma unroll
  for (int o = 0; o < 8; ++o) bias[o] = bs[o];
  float* ob = feat2 + ((size_t)n * NPIX + (y0 + lrow) * 64 + lcol) * 512 + oct * 32 + wid * 8;
#pragma unroll
  for (int j = 0; j < 4; ++j) {
    float4 v0, v1;
    v0.x = fmaxf(acc[0][j] + bias[0], 0.f);
    v0.y = fmaxf(acc[1][j] + bias[1], 0.f);
    v0.z = fmaxf(acc[2][j] + bias[2], 0.f);
    v0.w = fmaxf(acc[3][j] + bias[3], 0.f);
    v1.x = fmaxf(acc[4][j] + bias[4], 0.f);
    v1.y = fmaxf(acc[5][j] + bias[5], 0.f);
    v1.z = fmaxf(acc[6][j] + bias[6], 0.f);
    v1.w = fmaxf(acc[7][j] + bias[7], 0.f);
    *(float4*)(ob + (size_t)j * 512)     = v0;
    *(float4*)(ob + (size_t)j * 512 + 4) = v1;
  }
}

// ---------------- 1x1 convs (36 loc + 18 score) + bias -> out0/out1 ------
__global__ __launch_bounds__(256) void conv1_kernel(
    const float* __restrict__ feat2,
    const float* __restrict__ w_loc, const float* __restrict__ b_loc,
    const float* __restrict__ w_score, const float* __restrict__ b_score,
    float* __restrict__ out_locs, float* __restrict__ out_scores) {
  const int y = blockIdx.x, n = blockIdx.y;
  const int t = threadIdx.x;
  const int px = t & 63, grp = t >> 6;
  __shared__ float fl[64 * 129];
  __shared__ float wl[54 * 128];
  float acc[14];
#pragma unroll
  for (int k = 0; k < 14; ++k) acc[k] = 0.f;
  const float* fb = feat2 + ((size_t)n * NPIX + y * 64) * 512;
  for (int ch = 0; ch < 512; ch += 128) {
    for (int idx = t; idx < 64 * 128; idx += 256) {
      int p = idx >> 7, ic = idx & 127;
      fl[p * 129 + ic] = fb[(size_t)p * 512 + ch + ic];
    }
    for (int idx = t; idx < 54 * 128; idx += 256) {
      int c = idx >> 7, ic = idx & 127;
      wl[c * 128 + ic] = (c < 36) ? w_loc[c * 512 + ch + ic]
                                  : w_score[(c - 36) * 512 + ch + ic];
    }
    __syncthreads();
#pragma unroll 4
    for (int ic = 0; ic < 128; ++ic) {
      float f = fl[px * 129 + ic];
#pragma unroll
      for (int k = 0; k < 14; ++k) {
        int c = grp + 4 * k;
        if (c < 54) acc[k] = fmaf(wl[c * 128 + ic], f, acc[k]);
      }
    }
    __syncthreads();
  }
  size_t pix = (size_t)y * 64 + px;
#pragma unroll
  for (int k = 0; k < 14; ++k) {
    int c = grp + 4 * k;
    if (c < 36) {
      out_locs[((size_t)n * NPIX + pix) * 36 + c] = acc[k] + b_loc[c];
    } else if (c < 54) {
      out_scores[((size_t)n * NPIX + pix) * 18 + (c - 36)] = acc[k] + b_score[c - 36];
    }
  }
}

// ------------- anchors (f64->f32 like numpy) + decode + softmax + keys ----
__global__ __launch_bounds__(256) void decode_kernel(
    const float* __restrict__ locs, const float* __restrict__ scores,
    const int* __restrict__ ih, const int* __restrict__ iw,
    float* __restrict__ boxes, unsigned* __restrict__ keys,
    float* __restrict__ out_anchor) {
#pragma clang fp contract(off)
  int gid = blockIdx.x * 256 + threadIdx.x;
  if (gid >= 4 * NANCH) return;
  int n = gid / NANCH;
  int i = gid - n * NANCH;
  int a = i % 9;
  int pix = i / 9;
  int xq = pix & 63, yq = pix >> 6;
  int ri = a / 3, si = a - ri * 3;
  double ratio = (ri == 0) ? 0.5 : (ri == 1 ? 1.0 : 2.0);
  double scl   = (si == 0) ? 8.0 : (si == 1 ? 16.0 : 32.0);
  double hh = 16.0 * scl * sqrt(ratio);
  double ww = 16.0 * scl * sqrt(1.0 / ratio);
  float sx = (float)(xq * 16), sy = (float)(yq * 16);
  float ax1 = (float)(8.0 - ww * 0.5) + sx;
  float ay1 = (float)(8.0 - hh * 0.5) + sy;
  float ax2 = (float)(8.0 + ww * 0.5) + sx;
  float ay2 = (float)(8.0 + hh * 0.5) + sy;
  if (n == 0) {
    *(float4*)(out_anchor + (size_t)i * 4) = make_float4(ax1, ay1, ax2, ay2);
  }
  const float* lp = locs + ((size_t)n * NPIX + pix) * 36 + a * 4;
  float l0 = lp[0], l1 = lp[1], l2 = lp[2], l3 = lp[3];
  float aw = ax2 - ax1, ah = ay2 - ay1;
  float cx = ax1 + 0.5f * aw, cy = ay1 + 0.5f * ah;
  float ctrx = l0 * aw + cx, ctry = l1 * ah + cy;
  float nw = expf(l2) * aw, nh = expf(l3) * ah;
  float x1 = ctrx - 0.5f * nw, y1 = ctry - 0.5f * nh;
  float x2 = ctrx + 0.5f * nw, y2 = ctry + 0.5f * nh;
  float W = (float)iw[0], H = (float)ih[0];
  x1 = fminf(fmaxf(x1, 0.f), W);
  y1 = fminf(fmaxf(y1, 0.f), H);
  x2 = fminf(fmaxf(x2, 0.f), W);
  y2 = fminf(fmaxf(y2, 0.f), H);
  bool valid = ((x2 - x1) >= 16.f) && ((y2 - y1) >= 16.f);
  const float* sp = scores + ((size_t)n * NPIX + pix) * 18 + a * 2;
  float s0 = sp[0], s1 = sp[1];
  float mx = fmaxf(s0, s1);
  float e0 = expf(s0 - mx), e1 = expf(s1 - mx);
  float fg = e1 / (e0 + e1);
  float sc = valid ? fg : -1e9f;
  unsigned bb = __float_as_uint(sc);
  unsigned u = (bb & 0x80000000u) ? ~bb : (bb | 0x80000000u);  // ascending map
  keys[gid] = u;
  *(float4*)(boxes + (size_t)gid * 4) = make_float4(x1, y1, x2, y2);
}

// -------- exact stable top-3000 by rank counting (u64 total-order key) ----
__global__ __launch_bounds__(256) void rank_kernel(
    const unsigned* __restrict__ keys, const float* __restrict__ boxes,
    float* __restrict__ sboxes) {
  int n = blockIdx.y;
  int i = blockIdx.x * 256 + threadIdx.x;
  const unsigned* kb = keys + (size_t)n * NANCH;
  unsigned long long Ki = ((unsigned long long)(~kb[i]) << 32) | (unsigned)i;
  __shared__ unsigned long long tile[256];
  int rank = 0;
  for (int t0 = 0; t0 < NANCH; t0 += 256) {
    __syncthreads();
    tile[threadIdx.x] =
        ((unsigned long long)(~kb[t0 + threadIdx.x]) << 32) | (unsigned)(t0 + threadIdx.x);
    __syncthreads();
#pragma unroll 16
    for (int jj = 0; jj < 256; ++jj)
      rank += (tile[jj] < Ki) ? 1 : 0;
  }
  if (rank < PREN) {
    float4 bb = *(const float4*)(boxes + ((size_t)n * NANCH + i) * 4);
    *(float4*)(sboxes + ((size_t)n * PREN + rank) * 4) = bb;
  }
}

// ------------------ suppression bit-matrix (IoU > 0.7) --------------------
__global__ __launch_bounds__(256) void iou_kernel(
    const float* __restrict__ sboxes, unsigned long long* __restrict__ sup) {
#pragma clang fp contract(off)
  int n = blockIdx.y, i = blockIdx.x;
  const float* B = sboxes + (size_t)n * PREN * 4;
  float4 bi = *(const float4*)(B + (size_t)i * 4);
  float area_i = (bi.z - bi.x) * (bi.w - bi.y);
  int lane = threadIdx.x & 63, wv = threadIdx.x >> 6;
  unsigned long long* row = sup + ((size_t)n * PREN + i) * 64;
  for (int w0 = wv; w0 < 64; w0 += 4) {
    int j = w0 * 64 + lane;
    bool p = false;
    if (j < PREN) {
      float4 bj = *(const float4*)(B + (size_t)j * 4);
      float area_j = (bj.z - bj.x) * (bj.w - bj.y);
      float x1 = fmaxf(bi.x, bj.x), y1 = fmaxf(bi.y, bj.y);
      float x2 = fminf(bi.z, bj.z), y2 = fminf(bi.w, bj.w);
      float inter = fmaxf(x2 - x1, 0.f) * fmaxf(y2 - y1, 0.f);
      float iou = inter / (area_i + area_j - inter + 1e-9f);
      p = iou > 0.7f;
    }
    unsigned long long m = __ballot(p);
    if (lane == 0) row[w0] = m;
  }
}

// -------- sequential greedy sweep (1 wave/image) + emit 300 rois ----------
// Word-wise: kw = current keep-word tracked by all lanes; serial chain is
// ~5 VALU/step (no shfl on the chain); prefetch depth = 64 rows (~900 cyc).
__global__ __launch_bounds__(64) void nms_kernel(
    const unsigned long long* __restrict__ sup, const float* __restrict__ sboxes,
    float* __restrict__ rois, float* __restrict__ ridx) {
  int n = blockIdx.x;
  int lane = threadIdx.x;
  const unsigned long long* S = sup + (size_t)n * PREN * 64;
  unsigned long long buf[64];
#pragma unroll
  for (int bq = 0; bq < 64; ++bq) buf[bq] = S[(size_t)bq * 64 + lane];
  unsigned long long keep = (lane < 46) ? ~0ull
                          : (lane == 46 ? ((1ull << 56) - 1ull) : 0ull);  // 3000 bits
  for (int w = 0; w < 47; ++w) {
    unsigned long long kw = __shfl(keep, w);              // once per word
    unsigned long long gtmask = (lane > w) ? ~0ull : 0ull;
#pragma unroll
    for (int bq = 0; bq < 64; ++bq) {
      const int i = w * 64 + bq;
      unsigned long long r = buf[bq];
      if (i + 64 < PREN) buf[bq] = S[(size_t)(i + 64) * 64 + lane];  // prefetch
      unsigned long long rw = __shfl(r, w);               // off the serial chain
      unsigned long long amask = ((kw >> bq) & 1ull) ? ~0ull : 0ull;
      const unsigned long long fmask = (bq == 63) ? 0ull : ~((2ull << bq) - 1ull);
      kw &= ~(rw & fmask & amask);        // suppress future bits in this word
      keep &= ~(r & gtmask & amask);      // suppress future words
    }
    keep = (lane == w) ? kw : keep;       // commit word w
  }
  int cnt = __popcll(keep);
  int scn = cnt;
  for (int d = 1; d < 64; d <<= 1) {
    int v = __shfl_up(scn, d);
    if (lane >= d) scn += v;
  }
  int excl = scn - cnt;
  int total = __shfl(scn, 63);
  const float* SB = sboxes + (size_t)n * PREN * 4;
  unsigned long long kk = keep;
  int p = excl;
  while (kk) {
    int bpos = __ffsll(kk) - 1;
    kk &= kk - 1ull;
    if (p < POSTN) {
      float4 bb = *(const float4*)(SB + (size_t)(lane * 64 + bpos) * 4);
      *(float4*)(rois + ((size_t)n * POSTN + p) * 4) = bb;
    }
    ++p;
  }
  if (lane == 0) {
    float4 b0 = *(const float4*)SB;
    for (int q = total; q < POSTN; ++q)
      *(float4*)(rois + ((size_t)n * POSTN + q) * 4) = b0;
  }
  for (int q = lane; q < POSTN; q += 64) ridx[n * POSTN + q] = (float)n;
}

extern "C" void kernel_launch(void* const* d_in, const int* in_sizes, int n_in,
                              void* d_out, int out_size, void* d_ws, size_t ws_size,
                              hipStream_t stream) {
  const float* x       = (const float*)d_in[0];
  const float* w_conv  = (const float*)d_in[1];
  const float* b_conv  = (const float*)d_in[2];
  const float* w_score = (const float*)d_in[3];
  const float* b_score = (const float*)d_in[4];
  const float* w_loc   = (const float*)d_in[5];
  const float* b_loc   = (const float*)d_in[6];
  const int*   img_h   = (const int*)d_in[7];
  const int*   img_w   = (const int*)d_in[8];

  float* out        = (float*)d_out;
  float* out_locs   = out;                 // (4,36864,4)  589824
  float* out_scores = out + 589824;        // (4,36864,2)  294912
  float* out_rois   = out + 884736;        // (4,300,4)      4800
  float* out_ridx   = out + 889536;        // (4,300)        1200
  float* out_anchor = out + 890736;        // (1,36864,4)  147456

  // workspace: feat2 (33.5 MB) | region A: w2 (9.44 MB, dead after conv3)
  //            aliased by boxes/keys/sboxes/sup (9.26 MB, born at decode)
  float* feat2 = (float*)d_ws;                           // 8388608 f32
  float* A     = feat2 + (size_t)8388608;
  float* w2    = A;                                      // 2359296 f32
  float* boxes = A;                                      // 4*36864*4 f32
  unsigned* keys = (unsigned*)(boxes + 589824);          // 4*36864 u32
  float* sboxes = (float*)(keys + 147456);               // 4*3000*4 f32
  unsigned long long* sup = (unsigned long long*)(sboxes + 48000); // 4*3000*64 u64

  reshape_w_kernel<<<9216, 256, 0, stream>>>(w_conv, w2);
  conv3_kernel<<<dim3(16, 16, 4), 256, 0, stream>>>(x, w2, b_conv, feat2);
  conv1_kernel<<<dim3(64, 4), 256, 0, stream>>>(feat2, w_loc, b_loc,
                                                w_score, b_score, out_locs, out_scores);
  decode_kernel<<<576, 256, 0, stream>>>(out_locs, out_scores, img_h, img_w,
                                         boxes, keys, out_anchor);
  rank_kernel<<<dim3(144, 4), 256, 0, stream>>>(keys, boxes, sboxes);
  iou_kernel<<<dim3(PREN, 4), 256, 0, stream>>>(sboxes, sup);
  nms_kernel<<<4, 64, 0, stream>>>(sup, sboxes, out_rois, out_ridx);
}

// Round 4
// 1949.666 us; speedup vs baseline: 1.8605x; 1.1727x over previous
//
#include <hip/hip_runtime.h>
#include <cstdint>
#include <cmath>

#define HW 64
#define NPIX 4096          // 64*64
#define CIN 512
#define NANCH 36864        // 4096*9
#define PREN 3000
#define POSTN 300
#define ICL 8
#define NSLOT 13           // ceil(8*6*66 / 256)

// ---------------- W reshape: w[oc][ic][3][3] -> w2[g1][ic][k][o8] ---------
// g1 = oct*4 + wid (64 groups of 8 oc), oc = (g1>>2)*32 + (g1&3)*8 + o8
__global__ __launch_bounds__(256) void reshape_w_kernel(
    const float* __restrict__ w, float* __restrict__ w2) {
  int gid = blockIdx.x * 256 + threadIdx.x;
  if (gid >= 512 * 512 * 9) return;
  int o8  = gid & 7;
  int rem = gid >> 3;          // (g1*512 + ic)*9 + k
  int k   = rem % 9;
  int rem2 = rem / 9;          // g1*512 + ic
  int ic  = rem2 & 511;
  int g1  = rem2 >> 9;
  int oc  = (g1 >> 2) * 32 + (g1 & 3) * 8 + o8;
  w2[gid] = w[((size_t)oc * 512 + ic) * 9 + k];
}

// ---------------- 3x3 conv + bias + ReLU -> feat2 (NHWC) -----------------
// grid (16 oct, 16 ytile, 4 n), block 256 = 4 waves, 4 blocks/CU.
// Wave = 8 oc (wave-uniform -> W via s_load). Lane = 4 px (16x4 grid).
// Double-buffered LDS x staging; staging addresses precomputed in prologue.
__global__ __launch_bounds__(256, 4) void conv3_kernel(
    const float* __restrict__ x, const float* __restrict__ w2,
    const float* __restrict__ b, float* __restrict__ feat2) {
  const int oct = blockIdx.x;      // 0..15
  const int yt  = blockIdx.y;      // 0..15
  const int n   = blockIdx.z;
  const int t   = threadIdx.x;
  const int wid  = __builtin_amdgcn_readfirstlane(t >> 6);
  const int lane = t & 63;
  const int lrow = lane >> 4;          // 0..3
  const int lcol = (lane & 15) << 2;   // 0..60
  const int y0 = yt << 2;

  __shared__ float xs[2][ICL * 6 * 68];   // 2 x 13056 B

  float acc[8][4];
#pragma unroll
  for (int o = 0; o < 8; ++o)
#pragma unroll
    for (int j = 0; j < 4; ++j) acc[o][j] = 0.f;

  const float* xb = x + (size_t)n * CIN * NPIX;
  const float* __restrict__ wq = w2 + (size_t)(oct * 4 + wid) * (512 * 72);

  // ---- precompute staging slots (divides happen once) ----
  int  goff[NSLOT];    // element offset into xb for chunk 0
  int  laddr[NSLOT];   // LDS float offset within one buffer
  bool valid[NSLOT];   // in-bounds (zero-fill otherwise)
#pragma unroll
  for (int k = 0; k < NSLOT; ++k) {
    int s   = t + (k << 8);
    int icl = s / 396;
    int rem = s - icl * 396;
    int row = rem / 66;
    int c   = rem - row * 66;
    int yy = y0 - 1 + row;
    int xx = c - 1;
    bool act = (k < NSLOT - 1) || (t < 3168 - 256 * (NSLOT - 1));  // s < 3168
    valid[k] = act && ((unsigned)yy < 64u) && ((unsigned)xx < 64u);
    goff[k]  = icl * NPIX + yy * 64 + xx;
    laddr[k] = icl * 408 + row * 68 + c;
  }

  // ---- prologue: stage chunk 0 into buf 0 ----
  {
    float v[NSLOT];
#pragma unroll
    for (int k = 0; k < NSLOT; ++k) v[k] = valid[k] ? xb[goff[k]] : 0.f;
#pragma unroll
    for (int k = 0; k < NSLOT; ++k)
      if (k < NSLOT - 1 || t < 3168 - 256 * (NSLOT - 1)) xs[0][laddr[k]] = v[k];
  }

  for (int c = 0; c < 64; ++c) {
    const int cur = c & 1;
    // issue next chunk's global loads BEFORE the barrier (latency hidden by compute)
    float rn[NSLOT];
    if (c < 63) {
      const float* xn = xb + (size_t)(c + 1) * (ICL * NPIX);
#pragma unroll
      for (int k = 0; k < NSLOT; ++k) rn[k] = valid[k] ? xn[goff[k]] : 0.f;
    }
    __syncthreads();                      // buf[cur] ready
    const int icc = c * ICL;
#pragma unroll 1
    for (int icl = 0; icl < ICL; ++icl) {
      const float* __restrict__ wp = wq + (size_t)(icc + icl) * 72;  // uniform -> s_load
      const float* xp = &xs[cur][icl * 408 + lrow * 68 + lcol];
      float4 a0 = *(const float4*)(xp);
      float2 b0 = *(const float2*)(xp + 4);
      float4 a1 = *(const float4*)(xp + 68);
      float2 b1 = *(const float2*)(xp + 72);
      float4 a2 = *(const float4*)(xp + 136);
      float2 b2 = *(const float2*)(xp + 140);
      float xr[3][6] = {{a0.x, a0.y, a0.z, a0.w, b0.x, b0.y},
                        {a1.x, a1.y, a1.z, a1.w, b1.x, b1.y},
                        {a2.x, a2.y, a2.z, a2.w, b2.x, b2.y}};
#pragma unroll
      for (int r = 0; r < 3; ++r)
#pragma unroll
        for (int kx = 0; kx < 3; ++kx) {
          const int tap = r * 3 + kx;
#pragma unroll
          for (int o = 0; o < 8; ++o) {
            float wv = wp[tap * 8 + o];      // SGPR broadcast
#pragma unroll
            for (int j = 0; j < 4; ++j)
              acc[o][j] = fmaf(wv, xr[r][j + kx], acc[o][j]);
          }
        }
    }
    if (c < 63) {                          // write next chunk into other buffer
#pragma unroll
      for (int k = 0; k < NSLOT; ++k)
        if (k < NSLOT - 1 || t < 3168 - 256 * (NSLOT - 1)) xs[cur ^ 1][laddr[k]] = rn[k];
    }
  }

  const float* __restrict__ bs = b + oct * 32 + wid * 8;  // uniform
  float bias[8];
#pragma unroll
  for (int o = 0; o < 8; ++o) bias[o] = bs[o];
  float* ob = feat2 + ((size_t)n * NPIX + (y0 + lrow) * 64 + lcol) * 512 + oct * 32 + wid * 8;
#pragma unroll
  for (int j = 0; j < 4; ++j) {
    float4 v0, v1;
    v0.x = fmaxf(acc[0][j] + bias[0], 0.f);
    v0.y = fmaxf(acc[1][j] + bias[1], 0.f);
    v0.z = fmaxf(acc[2][j] + bias[2], 0.f);
    v0.w = fmaxf(acc[3][j] + bias[3], 0.f);
    v1.x = fmaxf(acc[4][j] + bias[4], 0.f);
    v1.y = fmaxf(acc[5][j] + bias[5], 0.f);
    v1.z = fmaxf(acc[6][j] + bias[6], 0.f);
    v1.w = fmaxf(acc[7][j] + bias[7], 0.f);
    *(float4*)(ob + (size_t)j * 512)     = v0;
    *(float4*)(ob + (size_t)j * 512 + 4) = v1;
  }
}

// ---------------- 1x1 convs (36 loc + 18 score) + bias -> out0/out1 ------
__global__ __launch_bounds__(256) void conv1_kernel(
    const float* __restrict__ feat2,
    const float* __restrict__ w_loc, const float* __restrict__ b_loc,
    const float* __restrict__ w_score, const float* __restrict__ b_score,
    float* __restrict__ out_locs, float* __restrict__ out_scores) {
  const int y = blockIdx.x, n = blockIdx.y;
  const int t = threadIdx.x;
  const int px = t & 63, grp = t >> 6;
  __shared__ float fl[64 * 129];
  __shared__ float wl[54 * 128];
  float acc[14];
#pragma unroll
  for (int k = 0; k < 14; ++k) acc[k] = 0.f;
  const float* fb = feat2 + ((size_t)n * NPIX + y * 64) * 512;
  for (int ch = 0; ch < 512; ch += 128) {
    for (int idx = t; idx < 64 * 128; idx += 256) {
      int p = idx >> 7, ic = idx & 127;
      fl[p * 129 + ic] = fb[(size_t)p * 512 + ch + ic];
    }
    for (int idx = t; idx < 54 * 128; idx += 256) {
      int c = idx >> 7, ic = idx & 127;
      wl[c * 128 + ic] = (c < 36) ? w_loc[c * 512 + ch + ic]
                                  : w_score[(c - 36) * 512 + ch + ic];
    }
    __syncthreads();
#pragma unroll 4
    for (int ic = 0; ic < 128; ++ic) {
      float f = fl[px * 129 + ic];
#pragma unroll
      for (int k = 0; k < 14; ++k) {
        int c = grp + 4 * k;
        if (c < 54) acc[k] = fmaf(wl[c * 128 + ic], f, acc[k]);
      }
    }
    __syncthreads();
  }
  size_t pix = (size_t)y * 64 + px;
#pragma unroll
  for (int k = 0; k < 14; ++k) {
    int c = grp + 4 * k;
    if (c < 36) {
      out_locs[((size_t)n * NPIX + pix) * 36 + c] = acc[k] + b_loc[c];
    } else if (c < 54) {
      out_scores[((size_t)n * NPIX + pix) * 18 + (c - 36)] = acc[k] + b_score[c - 36];
    }
  }
}

// ------------- anchors (f64->f32 like numpy) + decode + softmax + keys ----
__global__ __launch_bounds__(256) void decode_kernel(
    const float* __restrict__ locs, const float* __restrict__ scores,
    const int* __restrict__ ih, const int* __restrict__ iw,
    float* __restrict__ boxes, unsigned long long* __restrict__ keys64,
    float* __restrict__ out_anchor) {
#pragma clang fp contract(off)
  int gid = blockIdx.x * 256 + threadIdx.x;
  if (gid >= 4 * NANCH) return;
  int n = gid / NANCH;
  int i = gid - n * NANCH;
  int a = i % 9;
  int pix = i / 9;
  int xq = pix & 63, yq = pix >> 6;
  int ri = a / 3, si = a - ri * 3;
  double ratio = (ri == 0) ? 0.5 : (ri == 1 ? 1.0 : 2.0);
  double scl   = (si == 0) ? 8.0 : (si == 1 ? 16.0 : 32.0);
  double hh = 16.0 * scl * sqrt(ratio);
  double ww = 16.0 * scl * sqrt(1.0 / ratio);
  float sx = (float)(xq * 16), sy = (float)(yq * 16);
  float ax1 = (float)(8.0 - ww * 0.5) + sx;
  float ay1 = (float)(8.0 - hh * 0.5) + sy;
  float ax2 = (float)(8.0 + ww * 0.5) + sx;
  float ay2 = (float)(8.0 + hh * 0.5) + sy;
  if (n == 0) {
    *(float4*)(out_anchor + (size_t)i * 4) = make_float4(ax1, ay1, ax2, ay2);
  }
  const float* lp = locs + ((size_t)n * NPIX + pix) * 36 + a * 4;
  float l0 = lp[0], l1 = lp[1], l2 = lp[2], l3 = lp[3];
  float aw = ax2 - ax1, ah = ay2 - ay1;
  float cx = ax1 + 0.5f * aw, cy = ay1 + 0.5f * ah;
  float ctrx = l0 * aw + cx, ctry = l1 * ah + cy;
  float nw = expf(l2) * aw, nh = expf(l3) * ah;
  float x1 = ctrx - 0.5f * nw, y1 = ctry - 0.5f * nh;
  float x2 = ctrx + 0.5f * nw, y2 = ctry + 0.5f * nh;
  float W = (float)iw[0], H = (float)ih[0];
  x1 = fminf(fmaxf(x1, 0.f), W);
  y1 = fminf(fmaxf(y1, 0.f), H);
  x2 = fminf(fmaxf(x2, 0.f), W);
  y2 = fminf(fmaxf(y2, 0.f), H);
  bool valid = ((x2 - x1) >= 16.f) && ((y2 - y1) >= 16.f);
  const float* sp = scores + ((size_t)n * NPIX + pix) * 18 + a * 2;
  float s0 = sp[0], s1 = sp[1];
  float mx = fmaxf(s0, s1);
  float e0 = expf(s0 - mx), e1 = expf(s1 - mx);
  float fg = e1 / (e0 + e1);
  float sc = valid ? fg : -1e9f;
  unsigned bb = __float_as_uint(sc);
  unsigned u = (bb & 0x80000000u) ? ~bb : (bb | 0x80000000u);  // ascending map
  keys64[gid] = ((unsigned long long)(~u) << 32) | (unsigned)i; // asc = score desc, idx asc
  *(float4*)(boxes + (size_t)gid * 4) = make_float4(x1, y1, x2, y2);
}

// -------- exact stable top-3000 by rank counting; keys via uniform s_load --
__global__ __launch_bounds__(256) void rank_kernel(
    const unsigned long long* __restrict__ keys64, const float* __restrict__ boxes,
    float* __restrict__ sboxes) {
  int n = blockIdx.y;
  int i = blockIdx.x * 256 + threadIdx.x;
  const unsigned long long* __restrict__ kb = keys64 + (size_t)n * NANCH;
  unsigned long long Ki = kb[i];          // per-lane
  int rank = 0;
  for (int j = 0; j < NANCH; j += 8) {    // j uniform -> s_load_dwordxN batches
    rank += (kb[j + 0] < Ki) ? 1 : 0;
    rank += (kb[j + 1] < Ki) ? 1 : 0;
    rank += (kb[j + 2] < Ki) ? 1 : 0;
    rank += (kb[j + 3] < Ki) ? 1 : 0;
    rank += (kb[j + 4] < Ki) ? 1 : 0;
    rank += (kb[j + 5] < Ki) ? 1 : 0;
    rank += (kb[j + 6] < Ki) ? 1 : 0;
    rank += (kb[j + 7] < Ki) ? 1 : 0;
  }
  if (rank < PREN) {
    float4 bb = *(const float4*)(boxes + ((size_t)n * NANCH + i) * 4);
    *(float4*)(sboxes + ((size_t)n * PREN + rank) * 4) = bb;
  }
}

// ------------------ suppression bit-matrix (IoU > 0.7) --------------------
__global__ __launch_bounds__(256) void iou_kernel(
    const float* __restrict__ sboxes, unsigned long long* __restrict__ sup) {
#pragma clang fp contract(off)
  int n = blockIdx.y, i = blockIdx.x;
  const float* B = sboxes + (size_t)n * PREN * 4;
  float4 bi = *(const float4*)(B + (size_t)i * 4);
  float area_i = (bi.z - bi.x) * (bi.w - bi.y);
  int lane = threadIdx.x & 63, wv = threadIdx.x >> 6;
  unsigned long long* row = sup + ((size_t)n * PREN + i) * 64;
  for (int w0 = wv; w0 < 64; w0 += 4) {
    int j = w0 * 64 + lane;
    bool p = false;
    if (j < PREN) {
      float4 bj = *(const float4*)(B + (size_t)j * 4);
      float area_j = (bj.z - bj.x) * (bj.w - bj.y);
      float x1 = fmaxf(bi.x, bj.x), y1 = fmaxf(bi.y, bj.y);
      float x2 = fminf(bi.z, bj.z), y2 = fminf(bi.w, bj.w);
      float inter = fmaxf(x2 - x1, 0.f) * fmaxf(y2 - y1, 0.f);
      float iou = inter / (area_i + area_j - inter + 1e-9f);
      p = iou > 0.7f;
    }
    unsigned long long m = __ballot(p);
    if (lane == 0) row[w0] = m;
  }
}

// -------- sequential greedy sweep (1 wave/image) + emit 300 rois ----------
__global__ __launch_bounds__(64) void nms_kernel(
    const unsigned long long* __restrict__ sup, const float* __restrict__ sboxes,
    float* __restrict__ rois, float* __restrict__ ridx) {
  int n = blockIdx.x;
  int lane = threadIdx.x;
  const unsigned long long* S = sup + (size_t)n * PREN * 64;
  unsigned long long buf[64];
#pragma unroll
  for (int bq = 0; bq < 64; ++bq) buf[bq] = S[(size_t)bq * 64 + lane];
  unsigned long long keep = (lane < 46) ? ~0ull
                          : (lane == 46 ? ((1ull << 56) - 1ull) : 0ull);  // 3000 bits
  for (int w = 0; w < 47; ++w) {
    unsigned long long kw = __shfl(keep, w);
    unsigned long long gtmask = (lane > w) ? ~0ull : 0ull;
#pragma unroll
    for (int bq = 0; bq < 64; ++bq) {
      const int i = w * 64 + bq;
      unsigned long long r = buf[bq];
      if (i + 64 < PREN) buf[bq] = S[(size_t)(i + 64) * 64 + lane];
      unsigned long long rw = __shfl(r, w);
      unsigned long long amask = ((kw >> bq) & 1ull) ? ~0ull : 0ull;
      const unsigned long long fmask = (bq == 63) ? 0ull : ~((2ull << bq) - 1ull);
      kw &= ~(rw & fmask & amask);
      keep &= ~(r & gtmask & amask);
    }
    keep = (lane == w) ? kw : keep;
  }
  int cnt = __popcll(keep);
  int scn = cnt;
  for (int d = 1; d < 64; d <<= 1) {
    int v = __shfl_up(scn, d);
    if (lane >= d) scn += v;
  }
  int excl = scn - cnt;
  int total = __shfl(scn, 63);
  const float* SB = sboxes + (size_t)n * PREN * 4;
  unsigned long long kk = keep;
  int p = excl;
  while (kk) {
    int bpos = __ffsll(kk) - 1;
    kk &= kk - 1ull;
    if (p < POSTN) {
      float4 bb = *(const float4*)(SB + (size_t)(lane * 64 + bpos) * 4);
      *(float4*)(rois + ((size_t)n * POSTN + p) * 4) = bb;
    }
    ++p;
  }
  if (lane == 0) {
    float4 b0 = *(const float4*)SB;
    for (int q = total; q < POSTN; ++q)
      *(float4*)(rois + ((size_t)n * POSTN + q) * 4) = b0;
  }
  for (int q = lane; q < POSTN; q += 64) ridx[n * POSTN + q] = (float)n;
}

extern "C" void kernel_launch(void* const* d_in, const int* in_sizes, int n_in,
                              void* d_out, int out_size, void* d_ws, size_t ws_size,
                              hipStream_t stream) {
  const float* x       = (const float*)d_in[0];
  const float* w_conv  = (const float*)d_in[1];
  const float* b_conv  = (const float*)d_in[2];
  const float* w_score = (const float*)d_in[3];
  const float* b_score = (const float*)d_in[4];
  const float* w_loc   = (const float*)d_in[5];
  const float* b_loc   = (const float*)d_in[6];
  const int*   img_h   = (const int*)d_in[7];
  const int*   img_w   = (const int*)d_in[8];

  float* out        = (float*)d_out;
  float* out_locs   = out;                 // (4,36864,4)  589824
  float* out_scores = out + 589824;        // (4,36864,2)  294912
  float* out_rois   = out + 884736;        // (4,300,4)      4800
  float* out_ridx   = out + 889536;        // (4,300)        1200
  float* out_anchor = out + 890736;        // (1,36864,4)  147456

  // feat2 region (dead after conv1) hosts keys64 (born at decode).
  // region A: w2 (dead after conv3) aliased by boxes/sboxes/sup.
  float* feat2 = (float*)d_ws;                           // 8388608 f32
  unsigned long long* keys64 = (unsigned long long*)d_ws; // 4*36864 u64 (1.18 MB)
  float* A     = feat2 + (size_t)8388608;
  float* w2    = A;                                      // 2359296 f32
  float* boxes = A;                                      // 4*36864*4 f32
  float* sboxes = boxes + 589824;                        // 4*3000*4 f32
  unsigned long long* sup = (unsigned long long*)(sboxes + 48000); // 4*3000*64 u64

  reshape_w_kernel<<<9216, 256, 0, stream>>>(w_conv, w2);
  conv3_kernel<<<dim3(16, 16, 4), 256, 0, stream>>>(x, w2, b_conv, feat2);
  conv1_kernel<<<dim3(64, 4), 256, 0, stream>>>(feat2, w_loc, b_loc,
                                                w_score, b_score, out_locs, out_scores);
  decode_kernel<<<576, 256, 0, stream>>>(out_locs, out_scores, img_h, img_w,
                                         boxes, keys64, out_anchor);
  rank_kernel<<<dim3(144, 4), 256, 0, stream>>>(keys64, boxes, sboxes);
  iou_kernel<<<dim3(PREN, 4), 256, 0, stream>>>(sboxes, sup);
  nms_kernel<<<4, 64, 0, stream>>>(sup, sboxes, out_rois, out_ridx);
}

// Round 5
// 1613.501 us; speedup vs baseline: 2.2482x; 1.2083x over previous
//
#include <hip/hip_runtime.h>
#include <cstdint>
#include <cmath>

#define HW 64
#define NPIX 4096          // 64*64
#define CIN 512
#define NANCH 36864        // 4096*9
#define PREN 3000
#define POSTN 300
#define ICL3 8
#define NSLOT 21           // ceil(8*10*66 / 256), last slot: 160 threads

// ---------------- W reshape: w[oc][ic][3][3] -> w3[g][ic][tap][o4] --------
// g = oct*4 + wid (128 groups of 4 oc), oc = (g>>2)*16 + (g&3)*4 + o4
__global__ __launch_bounds__(256) void reshape_w_kernel(
    const float* __restrict__ w, float* __restrict__ w3) {
  int gid = blockIdx.x * 256 + threadIdx.x;
  if (gid >= 512 * 512 * 9) return;
  int o4  = gid & 3;
  int rem = gid >> 2;          // (g*512 + ic)*9 + tap
  int tap = rem % 9;
  int rem2 = rem / 9;          // g*512 + ic
  int ic  = rem2 & 511;
  int g   = rem2 >> 9;
  int oc  = (g >> 2) * 16 + (g & 3) * 4 + o4;
  w3[gid] = w[((size_t)oc * 512 + ic) * 9 + tap];
}

// ---------------- 3x3 conv + bias + ReLU -> feat2 (NHWC) -----------------
// grid (32 oct, 8 ytile, 4 n), block 256 = 4 waves, 3 blocks/CU (LDS-capped).
// Wave = 4 oc (SGPR double-buffered weights). Lane = 2 rows x 4 cols = 8 px.
#define CONV_STEP(ICLV, W) do {                                              \
    const float* xp = &xs[cur][(ICLV) * 680 + (rg * 2) * 68 + lcol];         \
    float xr[4][6];                                                          \
    _Pragma("unroll")                                                        \
    for (int rr = 0; rr < 4; ++rr) {                                         \
      float4 a4 = *(const float4*)(xp + rr * 68);                            \
      float2 a2 = *(const float2*)(xp + rr * 68 + 4);                        \
      xr[rr][0] = a4.x; xr[rr][1] = a4.y; xr[rr][2] = a4.z;                  \
      xr[rr][3] = a4.w; xr[rr][4] = a2.x; xr[rr][5] = a2.y;                  \
    }                                                                        \
    _Pragma("unroll")                                                        \
    for (int r = 0; r < 3; ++r)                                              \
    _Pragma("unroll")                                                        \
    for (int kx = 0; kx < 3; ++kx) {                                         \
      _Pragma("unroll")                                                      \
      for (int o = 0; o < 4; ++o) {                                          \
        const float wv = (W)[(r * 3 + kx) * 4 + o];                          \
        _Pragma("unroll")                                                    \
        for (int d = 0; d < 2; ++d)                                          \
        _Pragma("unroll")                                                    \
        for (int j = 0; j < 4; ++j)                                          \
          acc[o][d][j] = fmaf(wv, xr[d + r][j + kx], acc[o][d][j]);          \
      }                                                                      \
    }                                                                        \
  } while (0)

__global__ __launch_bounds__(256, 3) void conv3_kernel(
    const float* __restrict__ x, const float* __restrict__ w3,
    const float* __restrict__ b, float* __restrict__ feat2) {
  const int oct = blockIdx.x;      // 0..31 (16 oc per block)
  const int yt  = blockIdx.y;      // 0..7  (8 rows per block)
  const int n   = blockIdx.z;
  const int t   = threadIdx.x;
  const int wid  = __builtin_amdgcn_readfirstlane(t >> 6);
  const int lane = t & 63;
  const int rg = lane >> 4;          // 0..3, 2 rows each
  const int cg = lane & 15;          // 0..15, 4 cols each
  const int lcol = cg << 2;
  const int y0 = yt << 3;

  __shared__ float xs[2][ICL3 * 10 * 68];   // rows y0-1..y0+8, col c <-> xx=c-1

  float acc[4][2][4];
#pragma unroll
  for (int o = 0; o < 4; ++o)
#pragma unroll
    for (int d = 0; d < 2; ++d)
#pragma unroll
      for (int j = 0; j < 4; ++j) acc[o][d][j] = 0.f;

  const float* xb = x + (size_t)n * CIN * NPIX;
  const float* __restrict__ wq = w3 + (size_t)(oct * 4 + wid) * (512 * 36);

  // ---- staging slots (divides once): 8*10*66 = 5280 elems ----
  int  goff[NSLOT];
  int  laddr[NSLOT];
  bool val[NSLOT];
#pragma unroll
  for (int k = 0; k < NSLOT; ++k) {
    int s   = t + (k << 8);
    int icl = s / 660;
    int rem = s - icl * 660;
    int row = rem / 66;
    int c   = rem - row * 66;
    int yy = y0 - 1 + row;
    int xx = c - 1;
    bool act = (k < NSLOT - 1) || (t < 160);
    val[k]  = act && ((unsigned)yy < 64u) && ((unsigned)xx < 64u);
    goff[k] = icl * NPIX + yy * 64 + xx;
    laddr[k] = icl * 680 + row * 68 + c;
  }

  { // prologue: chunk 0 -> buf 0
    float v[NSLOT];
#pragma unroll
    for (int k = 0; k < NSLOT; ++k) v[k] = val[k] ? xb[goff[k]] : 0.f;
#pragma unroll
    for (int k = 0; k < NSLOT; ++k)
      if (k < NSLOT - 1 || t < 160) xs[0][laddr[k]] = v[k];
  }

  float wb0[36], wb1[36];
#pragma unroll
  for (int q = 0; q < 36; ++q) wb0[q] = wq[q];       // k=0 (uniform -> s_load)

  for (int cch = 0; cch < 64; ++cch) {
    const int cur = cch & 1;
    float rn[NSLOT];
    if (cch < 63) {                  // next chunk loads issued before barrier
      const float* xn = xb + (size_t)(cch + 1) * (ICL3 * NPIX);
#pragma unroll
      for (int k = 0; k < NSLOT; ++k) rn[k] = val[k] ? xn[goff[k]] : 0.f;
    }
    __syncthreads();
#pragma unroll 1
    for (int icl = 0; icl < ICL3; icl += 2) {
      const int k0 = (cch << 3) + icl;
      {  // prefetch k0+1 -> wb1 (hidden under even compute)
        const float* __restrict__ wn = wq + (size_t)(k0 + 1) * 36;
#pragma unroll
        for (int q = 0; q < 36; ++q) wb1[q] = wn[q];
      }
      CONV_STEP(icl, wb0);
      if (k0 + 2 < 512) {  // prefetch k0+2 -> wb0 (hidden under odd compute)
        const float* __restrict__ wn = wq + (size_t)(k0 + 2) * 36;
#pragma unroll
        for (int q = 0; q < 36; ++q) wb0[q] = wn[q];
      }
      CONV_STEP(icl + 1, wb1);
    }
    if (cch < 63) {
#pragma unroll
      for (int k = 0; k < NSLOT; ++k)
        if (k < NSLOT - 1 || t < 160) xs[cur ^ 1][laddr[k]] = rn[k];
    }
  }

  const float* __restrict__ bs = b + oct * 16 + wid * 4;   // uniform
  float b0 = bs[0], b1 = bs[1], b2 = bs[2], b3 = bs[3];
#pragma unroll
  for (int d = 0; d < 2; ++d) {
    int row = y0 + rg * 2 + d;
    float* ob = feat2 + ((size_t)n * NPIX + row * 64 + lcol) * 512 + oct * 16 + wid * 4;
#pragma unroll
    for (int j = 0; j < 4; ++j) {
      float4 v;
      v.x = fmaxf(acc[0][d][j] + b0, 0.f);
      v.y = fmaxf(acc[1][d][j] + b1, 0.f);
      v.z = fmaxf(acc[2][d][j] + b2, 0.f);
      v.w = fmaxf(acc[3][d][j] + b3, 0.f);
      *(float4*)(ob + (size_t)j * 512) = v;
    }
  }
}

// ---------------- 1x1 convs (36 loc + 18 score) + bias -> out0/out1 ------
__global__ __launch_bounds__(256) void conv1_kernel(
    const float* __restrict__ feat2,
    const float* __restrict__ w_loc, const float* __restrict__ b_loc,
    const float* __restrict__ w_score, const float* __restrict__ b_score,
    float* __restrict__ out_locs, float* __restrict__ out_scores) {
  const int y = blockIdx.x, n = blockIdx.y;
  const int t = threadIdx.x;
  const int px = t & 63, grp = t >> 6;
  __shared__ float fl[64 * 129];
  __shared__ float wl[54 * 128];
  float acc[14];
#pragma unroll
  for (int k = 0; k < 14; ++k) acc[k] = 0.f;
  const float* fb = feat2 + ((size_t)n * NPIX + y * 64) * 512;
  for (int ch = 0; ch < 512; ch += 128) {
    for (int idx = t; idx < 64 * 128; idx += 256) {
      int p = idx >> 7, ic = idx & 127;
      fl[p * 129 + ic] = fb[(size_t)p * 512 + ch + ic];
    }
    for (int idx = t; idx < 54 * 128; idx += 256) {
      int c = idx >> 7, ic = idx & 127;
      wl[c * 128 + ic] = (c < 36) ? w_loc[c * 512 + ch + ic]
                                  : w_score[(c - 36) * 512 + ch + ic];
    }
    __syncthreads();
#pragma unroll 4
    for (int ic = 0; ic < 128; ++ic) {
      float f = fl[px * 129 + ic];
#pragma unroll
      for (int k = 0; k < 14; ++k) {
        int c = grp + 4 * k;
        if (c < 54) acc[k] = fmaf(wl[c * 128 + ic], f, acc[k]);
      }
    }
    __syncthreads();
  }
  size_t pix = (size_t)y * 64 + px;
#pragma unroll
  for (int k = 0; k < 14; ++k) {
    int c = grp + 4 * k;
    if (c < 36) {
      out_locs[((size_t)n * NPIX + pix) * 36 + c] = acc[k] + b_loc[c];
    } else if (c < 54) {
      out_scores[((size_t)n * NPIX + pix) * 18 + (c - 36)] = acc[k] + b_score[c - 36];
    }
  }
}

// ------ anchors + decode + softmax + keys + fused 65536-bin histogram -----
__global__ __launch_bounds__(256) void decode_kernel(
    const float* __restrict__ locs, const float* __restrict__ scores,
    const int* __restrict__ ih, const int* __restrict__ iw,
    float* __restrict__ boxes, unsigned* __restrict__ keys,
    unsigned* __restrict__ hist, float* __restrict__ out_anchor) {
#pragma clang fp contract(off)
  int gid = blockIdx.x * 256 + threadIdx.x;
  int lane = threadIdx.x & 63;
  int n = gid / NANCH;
  int i = gid - n * NANCH;
  int a = i % 9;
  int pix = i / 9;
  int xq = pix & 63, yq = pix >> 6;
  int ri = a / 3, si = a - ri * 3;
  double ratio = (ri == 0) ? 0.5 : (ri == 1 ? 1.0 : 2.0);
  double scl   = (si == 0) ? 8.0 : (si == 1 ? 16.0 : 32.0);
  double hh = 16.0 * scl * sqrt(ratio);
  double ww = 16.0 * scl * sqrt(1.0 / ratio);
  float sx = (float)(xq * 16), sy = (float)(yq * 16);
  float ax1 = (float)(8.0 - ww * 0.5) + sx;
  float ay1 = (float)(8.0 - hh * 0.5) + sy;
  float ax2 = (float)(8.0 + ww * 0.5) + sx;
  float ay2 = (float)(8.0 + hh * 0.5) + sy;
  if (n == 0) {
    *(float4*)(out_anchor + (size_t)i * 4) = make_float4(ax1, ay1, ax2, ay2);
  }
  const float* lp = locs + ((size_t)n * NPIX + pix) * 36 + a * 4;
  float l0 = lp[0], l1 = lp[1], l2 = lp[2], l3 = lp[3];
  float aw = ax2 - ax1, ah = ay2 - ay1;
  float cx = ax1 + 0.5f * aw, cy = ay1 + 0.5f * ah;
  float ctrx = l0 * aw + cx, ctry = l1 * ah + cy;
  float nw = expf(l2) * aw, nh = expf(l3) * ah;
  float x1 = ctrx - 0.5f * nw, y1 = ctry - 0.5f * nh;
  float x2 = ctrx + 0.5f * nw, y2 = ctry + 0.5f * nh;
  float W = (float)iw[0], H = (float)ih[0];
  x1 = fminf(fmaxf(x1, 0.f), W);
  y1 = fminf(fmaxf(y1, 0.f), H);
  x2 = fminf(fmaxf(x2, 0.f), W);
  y2 = fminf(fmaxf(y2, 0.f), H);
  bool valid = ((x2 - x1) >= 16.f) && ((y2 - y1) >= 16.f);
  const float* sp = scores + ((size_t)n * NPIX + pix) * 18 + a * 2;
  float s0 = sp[0], s1 = sp[1];
  float mx = fmaxf(s0, s1);
  float e0 = expf(s0 - mx), e1 = expf(s1 - mx);
  float fg = e1 / (e0 + e1);
  float sc = valid ? fg : -1e9f;
  unsigned bb = __float_as_uint(sc);
  unsigned v = (bb & 0x80000000u) ? ~bb : (bb | 0x80000000u);  // ascending map
  keys[gid] = v;
  *(float4*)(boxes + (size_t)gid * 4) = make_float4(x1, y1, x2, y2);
  // histogram (invalid lanes all share one bin -> wave-aggregate that case)
  unsigned bin = v >> 16;
  unsigned long long mv = __ballot(!valid);
  if (!valid) {
    int leader = __ffsll(mv) - 1;
    if (lane == leader)
      atomicAdd(&hist[(size_t)n * 65536 + bin], (unsigned)__popcll(mv));
  } else {
    atomicAdd(&hist[(size_t)n * 65536 + bin], 1u);
  }
}

// ------- find threshold bin P: count(v>>16 >= P) >= PREN, minimal set -----
__global__ __launch_bounds__(256) void scan_kernel(
    const unsigned* __restrict__ hist, unsigned* __restrict__ cut) {
  int n = blockIdx.x;
  int t = threadIdx.x;
  const unsigned* h = hist + (size_t)n * 65536;
  __shared__ unsigned csum[256];
  unsigned s = 0;
  for (int bq = 0; bq < 256; ++bq) s += h[t * 256 + bq];
  csum[t] = s;
  __syncthreads();
  if (t == 0) {
    unsigned cum = 0;
    int c = 255;
    for (; c > 0; --c) {
      if (cum + csum[c] >= PREN) break;
      cum += csum[c];
    }
    unsigned P = (unsigned)(c * 256);
    for (int bq = 255; bq >= 0; --bq) {
      cum += h[c * 256 + bq];
      if (cum >= PREN) { P = (unsigned)(c * 256 + bq); break; }
    }
    cut[n] = P;
  }
}

// ---- compact candidates (v>>16 >= P) with wave-aggregated atomics --------
__global__ __launch_bounds__(256) void compact_kernel(
    const unsigned* __restrict__ keys, const unsigned* __restrict__ cut,
    unsigned* __restrict__ cnt, unsigned long long* __restrict__ cand) {
  int gid = blockIdx.x * 256 + threadIdx.x;
  int lane = threadIdx.x & 63;
  int n = gid / NANCH;
  int i = gid - n * NANCH;
  unsigned v = keys[gid];
  bool take = (v >> 16) >= cut[n];
  unsigned long long m = __ballot(take);
  if (take) {
    int leader = __ffsll(m) - 1;
    int tot = __popcll(m);
    int pre = __popcll(m & ((lane == 0) ? 0ull : (~0ull >> (64 - lane))));
    unsigned base = 0;
    if (lane == leader) base = atomicAdd(&cnt[n], (unsigned)tot);
    base = __shfl(base, leader);
    // key: bigger = earlier (score desc, idx asc via ~i)
    cand[(size_t)n * NANCH + base + pre] =
        ((unsigned long long)v << 32) | (unsigned)(~i);
  }
}

// ---- exact rank among candidates (== global rank) -> score-sorted boxes --
__global__ __launch_bounds__(256) void rank2_kernel(
    const unsigned long long* __restrict__ cand, const unsigned* __restrict__ cnt,
    const float* __restrict__ boxes, float* __restrict__ sboxes) {
  int n = blockIdx.y;
  int C = (int)cnt[n];
  if (blockIdx.x * 256 >= C) return;          // uniform early-out
  int t = threadIdx.x;
  int i = blockIdx.x * 256 + t;
  const unsigned long long* cb = cand + (size_t)n * NANCH;
  unsigned long long Ki = (i < C) ? cb[i] : 0ull;
  __shared__ unsigned long long tile[256];
  int rank = 0;
  for (int t0 = 0; t0 < C; t0 += 256) {
    __syncthreads();
    int j = t0 + t;
    tile[t] = (j < C) ? cb[j] : 0ull;         // 0 is never > a real key
    __syncthreads();
#pragma unroll 16
    for (int jj = 0; jj < 256; ++jj)
      rank += (tile[jj] > Ki) ? 1 : 0;
  }
  if (i < C && rank < PREN) {
    unsigned orig = ~(unsigned)(Ki & 0xffffffffull);
    float4 bb = *(const float4*)(boxes + ((size_t)n * NANCH + orig) * 4);
    *(float4*)(sboxes + ((size_t)n * PREN + rank) * 4) = bb;
  }
}

// ------------------ suppression bit-matrix (IoU > 0.7) --------------------
__global__ __launch_bounds__(256) void iou_kernel(
    const float* __restrict__ sboxes, unsigned long long* __restrict__ sup) {
#pragma clang fp contract(off)
  int n = blockIdx.y, i = blockIdx.x;
  const float* B = sboxes + (size_t)n * PREN * 4;
  float4 bi = *(const float4*)(B + (size_t)i * 4);
  float area_i = (bi.z - bi.x) * (bi.w - bi.y);
  int lane = threadIdx.x & 63, wv = threadIdx.x >> 6;
  unsigned long long* row = sup + ((size_t)n * PREN + i) * 64;
  for (int w0 = wv; w0 < 64; w0 += 4) {
    int j = w0 * 64 + lane;
    bool p = false;
    if (j < PREN) {
      float4 bj = *(const float4*)(B + (size_t)j * 4);
      float area_j = (bj.z - bj.x) * (bj.w - bj.y);
      float x1 = fmaxf(bi.x, bj.x), y1 = fmaxf(bi.y, bj.y);
      float x2 = fminf(bi.z, bj.z), y2 = fminf(bi.w, bj.w);
      float inter = fmaxf(x2 - x1, 0.f) * fmaxf(y2 - y1, 0.f);
      float iou = inter / (area_i + area_j - inter + 1e-9f);
      p = iou > 0.7f;
    }
    unsigned long long m = __ballot(p);
    if (lane == 0) row[w0] = m;
  }
}

// -------- word-wise greedy sweep (1 wave/image) + emit 300 rois -----------
__global__ __launch_bounds__(64) void nms_kernel(
    const unsigned long long* __restrict__ sup, const float* __restrict__ sboxes,
    float* __restrict__ rois, float* __restrict__ ridx) {
  int n = blockIdx.x;
  int lane = threadIdx.x;
  const unsigned long long* S = sup + (size_t)n * PREN * 64;
  unsigned long long buf[64];
#pragma unroll
  for (int bq = 0; bq < 64; ++bq) buf[bq] = S[(size_t)bq * 64 + lane];
  unsigned long long keep = (lane < 46) ? ~0ull
                          : (lane == 46 ? ((1ull << 56) - 1ull) : 0ull);  // 3000 bits
  for (int w = 0; w < 47; ++w) {
    unsigned long long kw = __shfl(keep, w);
    unsigned long long gtmask = (lane > w) ? ~0ull : 0ull;
#pragma unroll
    for (int bq = 0; bq < 64; ++bq) {
      const int i = w * 64 + bq;
      unsigned long long r = buf[bq];
      if (i + 64 < PREN) buf[bq] = S[(size_t)(i + 64) * 64 + lane];
      unsigned long long rw = __shfl(r, w);
      unsigned long long amask = ((kw >> bq) & 1ull) ? ~0ull : 0ull;
      const unsigned long long fmask = (bq == 63) ? 0ull : ~((2ull << bq) - 1ull);
      kw &= ~(rw & fmask & amask);
      keep &= ~(r & gtmask & amask);
    }
    keep = (lane == w) ? kw : keep;
  }
  int cnt = __popcll(keep);
  int scn = cnt;
  for (int d = 1; d < 64; d <<= 1) {
    int v = __shfl_up(scn, d);
    if (lane >= d) scn += v;
  }
  int excl = scn - cnt;
  int total = __shfl(scn, 63);
  const float* SB = sboxes + (size_t)n * PREN * 4;
  unsigned long long kk = keep;
  int p = excl;
  while (kk) {
    int bpos = __ffsll(kk) - 1;
    kk &= kk - 1ull;
    if (p < POSTN) {
      float4 bb = *(const float4*)(SB + (size_t)(lane * 64 + bpos) * 4);
      *(float4*)(rois + ((size_t)n * POSTN + p) * 4) = bb;
    }
    ++p;
  }
  if (lane == 0) {
    float4 b0 = *(const float4*)SB;
    for (int q = total; q < POSTN; ++q)
      *(float4*)(rois + ((size_t)n * POSTN + q) * 4) = b0;
  }
  for (int q = lane; q < POSTN; q += 64) ridx[n * POSTN + q] = (float)n;
}

extern "C" void kernel_launch(void* const* d_in, const int* in_sizes, int n_in,
                              void* d_out, int out_size, void* d_ws, size_t ws_size,
                              hipStream_t stream) {
  const float* x       = (const float*)d_in[0];
  const float* w_conv  = (const float*)d_in[1];
  const float* b_conv  = (const float*)d_in[2];
  const float* w_score = (const float*)d_in[3];
  const float* b_score = (const float*)d_in[4];
  const float* w_loc   = (const float*)d_in[5];
  const float* b_loc   = (const float*)d_in[6];
  const int*   img_h   = (const int*)d_in[7];
  const int*   img_w   = (const int*)d_in[8];

  float* out        = (float*)d_out;
  float* out_locs   = out;                 // (4,36864,4)  589824
  float* out_scores = out + 589824;        // (4,36864,2)  294912
  float* out_rois   = out + 884736;        // (4,300,4)      4800
  float* out_ridx   = out + 889536;        // (4,300)        1200
  float* out_anchor = out + 890736;        // (1,36864,4)  147456

  // ws layout (floats unless noted):
  // feat2 33.55MB | region A: w3 9.44MB (dead after conv3) aliased by
  // boxes/keys/sboxes/sup (9.28MB) | hist 1MB + cut/cnt | cand 1.18MB
  float* feat2 = (float*)d_ws;                            // 8388608 f32
  float* A     = feat2 + (size_t)8388608;
  float* w3    = A;                                       // 2359296 f32
  float* boxes = A;                                       // 589824 f32
  unsigned* keys = (unsigned*)(boxes + 589824);           // 147456 u32
  float* sboxes  = (float*)(keys + 147456);               // 48000 f32
  unsigned long long* sup = (unsigned long long*)(sboxes + 48000); // 768000 u64
  unsigned* hist = (unsigned*)(A + 2359296);              // 262144 u32
  unsigned* cut  = hist + 262144;                         // 4 u32
  unsigned* cnt  = cut + 4;                               // 4 u32 (+pad to 64B)
  unsigned long long* cand = (unsigned long long*)(hist + 262144 + 16); // 147456 u64

  hipMemsetAsync(hist, 0, 262144 * 4 + 64, stream);       // hist + cut + cnt
  reshape_w_kernel<<<9216, 256, 0, stream>>>(w_conv, w3);
  conv3_kernel<<<dim3(32, 8, 4), 256, 0, stream>>>(x, w3, b_conv, feat2);
  conv1_kernel<<<dim3(64, 4), 256, 0, stream>>>(feat2, w_loc, b_loc,
                                                w_score, b_score, out_locs, out_scores);
  decode_kernel<<<576, 256, 0, stream>>>(out_locs, out_scores, img_h, img_w,
                                         boxes, keys, hist, out_anchor);
  scan_kernel<<<4, 256, 0, stream>>>(hist, cut);
  compact_kernel<<<576, 256, 0, stream>>>(keys, cut, cnt, cand);
  rank2_kernel<<<dim3(144, 4), 256, 0, stream>>>(cand, cnt, boxes, sboxes);
  iou_kernel<<<dim3(PREN, 4), 256, 0, stream>>>(sboxes, sup);
  nms_kernel<<<4, 64, 0, stream>>>(sup, sboxes, out_rois, out_ridx);
}

// Round 6
// 1365.982 us; speedup vs baseline: 2.6556x; 1.1812x over previous
//
#include <hip/hip_runtime.h>
#include <cstdint>
#include <cmath>

#define HW 64
#define NPIX 4096          // 64*64
#define CIN 512
#define NANCH 36864        // 4096*9
#define PREN 3000
#define POSTN 300
#define ICL 8
#define NSLOT 13           // ceil(8*6*66 / 256), last slot: 96 threads

// ------ W reshape: w[oc][ic][3][3] -> w4[g][ic][h][tap][o4] ---------------
// g = oct*4 + wid (64 groups of 8 oc), oc = (g>>2)*32 + (g&3)*8 + h*4 + o4
__global__ __launch_bounds__(256) void reshape_w_kernel(
    const float* __restrict__ w, float* __restrict__ w4) {
  int gid = blockIdx.x * 256 + threadIdx.x;
  if (gid >= 512 * 512 * 9) return;
  int o4  = gid & 3;
  int r   = gid >> 2;          // ((g*512+ic)*2+h)*9 + tap
  int tap = r % 9;
  int r2  = r / 9;             // (g*512+ic)*2 + h
  int h   = r2 & 1;
  int r3  = r2 >> 1;           // g*512 + ic
  int ic  = r3 & 511;
  int g   = r3 >> 9;
  int oc  = (g >> 2) * 32 + (g & 3) * 8 + h * 4 + o4;
  w4[gid] = w[((size_t)oc * 512 + ic) * 9 + tap];
}

// ---------------- 3x3 conv + bias + ReLU -> feat2 (NHWC) -----------------
// grid (16 oct, 16 ytile, 4 n), block 256 = 4 waves, 4 blocks/CU.
// Wave = 8 oc; weights stream through 2x36 SGPR buffers, prefetched one
// half-icl (144 FMA) ahead so s_load latency hides under compute and the
// stream crosses chunk barriers. Lane = 1 row x 4 cols; LDS x double-buffer.
#define WLOAD(DST, UPTR) do {                                                \
    _Pragma("unroll")                                                        \
    for (int q = 0; q < 36; ++q) (DST)[q] = (UPTR)[q];                       \
  } while (0)

#define CONV_HALF(W, OB) do {                                                \
    _Pragma("unroll")                                                        \
    for (int r = 0; r < 3; ++r)                                              \
    _Pragma("unroll")                                                        \
    for (int kx = 0; kx < 3; ++kx) {                                         \
      _Pragma("unroll")                                                      \
      for (int o = 0; o < 4; ++o) {                                          \
        const float wv = (W)[(r * 3 + kx) * 4 + o];                          \
        _Pragma("unroll")                                                    \
        for (int j = 0; j < 4; ++j)                                          \
          acc[(OB) + o][j] = fmaf(wv, xr[r][j + kx], acc[(OB) + o][j]);      \
      }                                                                      \
    }                                                                        \
  } while (0)

__global__ __launch_bounds__(256, 4) void conv3_kernel(
    const float* __restrict__ x, const float* __restrict__ w4,
    const float* __restrict__ b, float* __restrict__ feat2) {
  const int oct = blockIdx.x;      // 0..15
  const int yt  = blockIdx.y;      // 0..15
  const int n   = blockIdx.z;
  const int t   = threadIdx.x;
  const int wid  = __builtin_amdgcn_readfirstlane(t >> 6);
  const int lane = t & 63;
  const int lrow = lane >> 4;          // 0..3
  const int lcol = (lane & 15) << 2;   // 0..60
  const int y0 = yt << 2;

  __shared__ float xs[2][ICL * 6 * 68];   // 2 x 13056 B

  float acc[8][4];
#pragma unroll
  for (int o = 0; o < 8; ++o)
#pragma unroll
    for (int j = 0; j < 4; ++j) acc[o][j] = 0.f;

  const float* xb = x + (size_t)n * CIN * NPIX;
  const float* __restrict__ wq = w4 + (size_t)(oct * 4 + wid) * (512 * 72);

  // ---- staging slots (divides once): 8*6*66 = 3168 elems ----
  int  goff[NSLOT];
  int  laddr[NSLOT];
  bool val[NSLOT];
#pragma unroll
  for (int k = 0; k < NSLOT; ++k) {
    int s   = t + (k << 8);
    int icl = s / 396;
    int rem = s - icl * 396;
    int row = rem / 66;
    int c   = rem - row * 66;
    int yy = y0 - 1 + row;
    int xx = c - 1;
    bool act = (k < NSLOT - 1) || (t < 96);
    val[k]  = act && ((unsigned)yy < 64u) && ((unsigned)xx < 64u);
    goff[k] = icl * NPIX + yy * 64 + xx;
    laddr[k] = icl * 408 + row * 68 + c;
  }

  { // prologue: chunk 0 -> buf 0
    float v[NSLOT];
#pragma unroll
    for (int k = 0; k < NSLOT; ++k) v[k] = val[k] ? xb[goff[k]] : 0.f;
#pragma unroll
    for (int k = 0; k < NSLOT; ++k)
      if (k < NSLOT - 1 || t < 96) xs[0][laddr[k]] = v[k];
  }

  float wbA[36], wbB[36];
  WLOAD(wbA, wq);                         // unit 0

  for (int cch = 0; cch < 64; ++cch) {
    const int cur = cch & 1;
    float rn[NSLOT];
    if (cch < 63) {                       // next x chunk issued before barrier
      const float* xn = xb + (size_t)(cch + 1) * (ICL * NPIX);
#pragma unroll
      for (int k = 0; k < NSLOT; ++k) rn[k] = val[k] ? xn[goff[k]] : 0.f;
    }
    __syncthreads();                      // buf[cur] ready
#pragma unroll 1
    for (int icl = 0; icl < ICL; ++icl) {
      const int u0 = (cch << 4) + (icl << 1);    // unit in wbA
      const float* xp = &xs[cur][icl * 408 + lrow * 68 + lcol];
      float4 a0 = *(const float4*)(xp);
      float2 b0 = *(const float2*)(xp + 4);
      float4 a1 = *(const float4*)(xp + 68);
      float2 b1 = *(const float2*)(xp + 72);
      float4 a2 = *(const float4*)(xp + 136);
      float2 b2 = *(const float2*)(xp + 140);
      float xr[3][6] = {{a0.x, a0.y, a0.z, a0.w, b0.x, b0.y},
                        {a1.x, a1.y, a1.z, a1.w, b1.x, b1.y},
                        {a2.x, a2.y, a2.z, a2.w, b2.x, b2.y}};
      WLOAD(wbB, wq + (size_t)(u0 + 1) * 36);    // prefetch half B
      CONV_HALF(wbA, 0);                         // oc 0..3 (144 FMA)
      {
        const int un = (u0 + 2 < 1024) ? (u0 + 2) : 1023;
        WLOAD(wbA, wq + (size_t)un * 36);        // prefetch next half A
      }
      CONV_HALF(wbB, 4);                         // oc 4..7 (144 FMA)
    }
    if (cch < 63) {
#pragma unroll
      for (int k = 0; k < NSLOT; ++k)
        if (k < NSLOT - 1 || t < 96) xs[cur ^ 1][laddr[k]] = rn[k];
    }
  }

  const float* __restrict__ bs = b + oct * 32 + wid * 8;  // uniform
  float bias[8];
#pragma unroll
  for (int o = 0; o < 8; ++o) bias[o] = bs[o];
  float* ob = feat2 + ((size_t)n * NPIX + (y0 + lrow) * 64 + lcol) * 512 + oct * 32 + wid * 8;
#pragma unroll
  for (int j = 0; j < 4; ++j) {
    float4 v0, v1;
    v0.x = fmaxf(acc[0][j] + bias[0], 0.f);
    v0.y = fmaxf(acc[1][j] + bias[1], 0.f);
    v0.z = fmaxf(acc[2][j] + bias[2], 0.f);
    v0.w = fmaxf(acc[3][j] + bias[3], 0.f);
    v1.x = fmaxf(acc[4][j] + bias[4], 0.f);
    v1.y = fmaxf(acc[5][j] + bias[5], 0.f);
    v1.z = fmaxf(acc[6][j] + bias[6], 0.f);
    v1.w = fmaxf(acc[7][j] + bias[7], 0.f);
    *(float4*)(ob + (size_t)j * 512)     = v0;
    *(float4*)(ob + (size_t)j * 512 + 4) = v1;
  }
}

// ---------------- 1x1 convs (36 loc + 18 score) + bias -> out0/out1 ------
__global__ __launch_bounds__(256) void conv1_kernel(
    const float* __restrict__ feat2,
    const float* __restrict__ w_loc, const float* __restrict__ b_loc,
    const float* __restrict__ w_score, const float* __restrict__ b_score,
    float* __restrict__ out_locs, float* __restrict__ out_scores) {
  const int y = blockIdx.x, n = blockIdx.y;
  const int t = threadIdx.x;
  const int px = t & 63, grp = t >> 6;
  __shared__ float fl[64 * 129];
  __shared__ float wl[54 * 128];
  float acc[14];
#pragma unroll
  for (int k = 0; k < 14; ++k) acc[k] = 0.f;
  const float* fb = feat2 + ((size_t)n * NPIX + y * 64) * 512;
  for (int ch = 0; ch < 512; ch += 128) {
    for (int idx = t; idx < 64 * 128; idx += 256) {
      int p = idx >> 7, ic = idx & 127;
      fl[p * 129 + ic] = fb[(size_t)p * 512 + ch + ic];
    }
    for (int idx = t; idx < 54 * 128; idx += 256) {
      int c = idx >> 7, ic = idx & 127;
      wl[c * 128 + ic] = (c < 36) ? w_loc[c * 512 + ch + ic]
                                  : w_score[(c - 36) * 512 + ch + ic];
    }
    __syncthreads();
#pragma unroll 4
    for (int ic = 0; ic < 128; ++ic) {
      float f = fl[px * 129 + ic];
#pragma unroll
      for (int k = 0; k < 14; ++k) {
        int c = grp + 4 * k;
        if (c < 54) acc[k] = fmaf(wl[c * 128 + ic], f, acc[k]);
      }
    }
    __syncthreads();
  }
  size_t pix = (size_t)y * 64 + px;
#pragma unroll
  for (int k = 0; k < 14; ++k) {
    int c = grp + 4 * k;
    if (c < 36) {
      out_locs[((size_t)n * NPIX + pix) * 36 + c] = acc[k] + b_loc[c];
    } else if (c < 54) {
      out_scores[((size_t)n * NPIX + pix) * 18 + (c - 36)] = acc[k] + b_score[c - 36];
    }
  }
}

// ------ anchors + decode + softmax + keys + fused 65536-bin histogram -----
__global__ __launch_bounds__(256) void decode_kernel(
    const float* __restrict__ locs, const float* __restrict__ scores,
    const int* __restrict__ ih, const int* __restrict__ iw,
    float* __restrict__ boxes, unsigned* __restrict__ keys,
    unsigned* __restrict__ hist, float* __restrict__ out_anchor) {
#pragma clang fp contract(off)
  int gid = blockIdx.x * 256 + threadIdx.x;
  int lane = threadIdx.x & 63;
  int n = gid / NANCH;
  int i = gid - n * NANCH;
  int a = i % 9;
  int pix = i / 9;
  int xq = pix & 63, yq = pix >> 6;
  int ri = a / 3, si = a - ri * 3;
  double ratio = (ri == 0) ? 0.5 : (ri == 1 ? 1.0 : 2.0);
  double scl   = (si == 0) ? 8.0 : (si == 1 ? 16.0 : 32.0);
  double hh = 16.0 * scl * sqrt(ratio);
  double ww = 16.0 * scl * sqrt(1.0 / ratio);
  float sx = (float)(xq * 16), sy = (float)(yq * 16);
  float ax1 = (float)(8.0 - ww * 0.5) + sx;
  float ay1 = (float)(8.0 - hh * 0.5) + sy;
  float ax2 = (float)(8.0 + ww * 0.5) + sx;
  float ay2 = (float)(8.0 + hh * 0.5) + sy;
  if (n == 0) {
    *(float4*)(out_anchor + (size_t)i * 4) = make_float4(ax1, ay1, ax2, ay2);
  }
  const float* lp = locs + ((size_t)n * NPIX + pix) * 36 + a * 4;
  float l0 = lp[0], l1 = lp[1], l2 = lp[2], l3 = lp[3];
  float aw = ax2 - ax1, ah = ay2 - ay1;
  float cx = ax1 + 0.5f * aw, cy = ay1 + 0.5f * ah;
  float ctrx = l0 * aw + cx, ctry = l1 * ah + cy;
  float nw = expf(l2) * aw, nh = expf(l3) * ah;
  float x1 = ctrx - 0.5f * nw, y1 = ctry - 0.5f * nh;
  float x2 = ctrx + 0.5f * nw, y2 = ctry + 0.5f * nh;
  float W = (float)iw[0], H = (float)ih[0];
  x1 = fminf(fmaxf(x1, 0.f), W);
  y1 = fminf(fmaxf(y1, 0.f), H);
  x2 = fminf(fmaxf(x2, 0.f), W);
  y2 = fminf(fmaxf(y2, 0.f), H);
  bool valid = ((x2 - x1) >= 16.f) && ((y2 - y1) >= 16.f);
  const float* sp = scores + ((size_t)n * NPIX + pix) * 18 + a * 2;
  float s0 = sp[0], s1 = sp[1];
  float mx = fmaxf(s0, s1);
  float e0 = expf(s0 - mx), e1 = expf(s1 - mx);
  float fg = e1 / (e0 + e1);
  float sc = valid ? fg : -1e9f;
  unsigned bb = __float_as_uint(sc);
  unsigned v = (bb & 0x80000000u) ? ~bb : (bb | 0x80000000u);  // ascending map
  keys[gid] = v;
  *(float4*)(boxes + (size_t)gid * 4) = make_float4(x1, y1, x2, y2);
  unsigned bin = v >> 16;
  unsigned long long mv = __ballot(!valid);
  if (!valid) {
    int leader = __ffsll(mv) - 1;
    if (lane == leader)
      atomicAdd(&hist[(size_t)n * 65536 + bin], (unsigned)__popcll(mv));
  } else {
    atomicAdd(&hist[(size_t)n * 65536 + bin], 1u);
  }
}

// ------- find threshold bin P: count(v>>16 >= P) >= PREN, minimal set -----
__global__ __launch_bounds__(256) void scan_kernel(
    const unsigned* __restrict__ hist, unsigned* __restrict__ cut) {
  int n = blockIdx.x;
  int t = threadIdx.x;
  const unsigned* h = hist + (size_t)n * 65536;
  __shared__ unsigned csum[256];
  unsigned s = 0;
  for (int bq = 0; bq < 256; ++bq) s += h[t * 256 + bq];
  csum[t] = s;
  __syncthreads();
  if (t == 0) {
    unsigned cum = 0;
    int c = 255;
    for (; c > 0; --c) {
      if (cum + csum[c] >= PREN) break;
      cum += csum[c];
    }
    unsigned P = (unsigned)(c * 256);
    for (int bq = 255; bq >= 0; --bq) {
      cum += h[c * 256 + bq];
      if (cum >= PREN) { P = (unsigned)(c * 256 + bq); break; }
    }
    cut[n] = P;
  }
}

// ---- compact candidates (v>>16 >= P) with wave-aggregated atomics --------
__global__ __launch_bounds__(256) void compact_kernel(
    const unsigned* __restrict__ keys, const unsigned* __restrict__ cut,
    unsigned* __restrict__ cnt, unsigned long long* __restrict__ cand) {
  int gid = blockIdx.x * 256 + threadIdx.x;
  int lane = threadIdx.x & 63;
  int n = gid / NANCH;
  int i = gid - n * NANCH;
  unsigned v = keys[gid];
  bool take = (v >> 16) >= cut[n];
  unsigned long long m = __ballot(take);
  if (take) {
    int leader = __ffsll(m) - 1;
    int tot = __popcll(m);
    int pre = __popcll(m & ((lane == 0) ? 0ull : (~0ull >> (64 - lane))));
    unsigned base = 0;
    if (lane == leader) base = atomicAdd(&cnt[n], (unsigned)tot);
    base = __shfl(base, leader);
    cand[(size_t)n * NANCH + base + pre] =
        ((unsigned long long)v << 32) | (unsigned)(~i);
  }
}

// ---- exact rank among candidates (== global rank) -> score-sorted boxes --
__global__ __launch_bounds__(256) void rank2_kernel(
    const unsigned long long* __restrict__ cand, const unsigned* __restrict__ cnt,
    const float* __restrict__ boxes, float* __restrict__ sboxes) {
  int n = blockIdx.y;
  int C = (int)cnt[n];
  if (blockIdx.x * 256 >= C) return;
  int t = threadIdx.x;
  int i = blockIdx.x * 256 + t;
  const unsigned long long* cb = cand + (size_t)n * NANCH;
  unsigned long long Ki = (i < C) ? cb[i] : 0ull;
  __shared__ unsigned long long tile[256];
  int rank = 0;
  for (int t0 = 0; t0 < C; t0 += 256) {
    __syncthreads();
    int j = t0 + t;
    tile[t] = (j < C) ? cb[j] : 0ull;
    __syncthreads();
#pragma unroll 16
    for (int jj = 0; jj < 256; ++jj)
      rank += (tile[jj] > Ki) ? 1 : 0;
  }
  if (i < C && rank < PREN) {
    unsigned orig = ~(unsigned)(Ki & 0xffffffffull);
    float4 bb = *(const float4*)(boxes + ((size_t)n * NANCH + orig) * 4);
    *(float4*)(sboxes + ((size_t)n * PREN + rank) * 4) = bb;
  }
}

// ------------------ suppression bit-matrix (IoU > 0.7) --------------------
__global__ __launch_bounds__(256) void iou_kernel(
    const float* __restrict__ sboxes, unsigned long long* __restrict__ sup) {
#pragma clang fp contract(off)
  int n = blockIdx.y, i = blockIdx.x;
  const float* B = sboxes + (size_t)n * PREN * 4;
  float4 bi = *(const float4*)(B + (size_t)i * 4);
  float area_i = (bi.z - bi.x) * (bi.w - bi.y);
  int lane = threadIdx.x & 63, wv = threadIdx.x >> 6;
  unsigned long long* row = sup + ((size_t)n * PREN + i) * 64;
  for (int w0 = wv; w0 < 64; w0 += 4) {
    int j = w0 * 64 + lane;
    bool p = false;
    if (j < PREN) {
      float4 bj = *(const float4*)(B + (size_t)j * 4);
      float area_j = (bj.z - bj.x) * (bj.w - bj.y);
      float x1 = fmaxf(bi.x, bj.x), y1 = fmaxf(bi.y, bj.y);
      float x2 = fminf(bi.z, bj.z), y2 = fminf(bi.w, bj.w);
      float inter = fmaxf(x2 - x1, 0.f) * fmaxf(y2 - y1, 0.f);
      float iou = inter / (area_i + area_j - inter + 1e-9f);
      p = iou > 0.7f;
    }
    unsigned long long m = __ballot(p);
    if (lane == 0) row[w0] = m;
  }
}

// -------- word-wise greedy sweep (1 wave/image) + emit 300 rois -----------
__global__ __launch_bounds__(64) void nms_kernel(
    const unsigned long long* __restrict__ sup, const float* __restrict__ sboxes,
    float* __restrict__ rois, float* __restrict__ ridx) {
  int n = blockIdx.x;
  int lane = threadIdx.x;
  const unsigned long long* S = sup + (size_t)n * PREN * 64;
  unsigned long long buf[64];
#pragma unroll
  for (int bq = 0; bq < 64; ++bq) buf[bq] = S[(size_t)bq * 64 + lane];
  unsigned long long keep = (lane < 46) ? ~0ull
                          : (lane == 46 ? ((1ull << 56) - 1ull) : 0ull);  // 3000 bits
  for (int w = 0; w < 47; ++w) {
    unsigned long long kw = __shfl(keep, w);
    unsigned long long gtmask = (lane > w) ? ~0ull : 0ull;
#pragma unroll
    for (int bq = 0; bq < 64; ++bq) {
      const int i = w * 64 + bq;
      unsigned long long r = buf[bq];
      if (i + 64 < PREN) buf[bq] = S[(size_t)(i + 64) * 64 + lane];
      unsigned long long rw = __shfl(r, w);
      unsigned long long amask = ((kw >> bq) & 1ull) ? ~0ull : 0ull;
      const unsigned long long fmask = (bq == 63) ? 0ull : ~((2ull << bq) - 1ull);
      kw &= ~(rw & fmask & amask);
      keep &= ~(r & gtmask & amask);
    }
    keep = (lane == w) ? kw : keep;
  }
  int cnt = __popcll(keep);
  int scn = cnt;
  for (int d = 1; d < 64; d <<= 1) {
    int v = __shfl_up(scn, d);
    if (lane >= d) scn += v;
  }
  int excl = scn - cnt;
  int total = __shfl(scn, 63);
  const float* SB = sboxes + (size_t)n * PREN * 4;
  unsigned long long kk = keep;
  int p = excl;
  while (kk) {
    int bpos = __ffsll(kk) - 1;
    kk &= kk - 1ull;
    if (p < POSTN) {
      float4 bb = *(const float4*)(SB + (size_t)(lane * 64 + bpos) * 4);
      *(float4*)(rois + ((size_t)n * POSTN + p) * 4) = bb;
    }
    ++p;
  }
  if (lane == 0) {
    float4 b0 = *(const float4*)SB;
    for (int q = total; q < POSTN; ++q)
      *(float4*)(rois + ((size_t)n * POSTN + q) * 4) = b0;
  }
  for (int q = lane; q < POSTN; q += 64) ridx[n * POSTN + q] = (float)n;
}

extern "C" void kernel_launch(void* const* d_in, const int* in_sizes, int n_in,
                              void* d_out, int out_size, void* d_ws, size_t ws_size,
                              hipStream_t stream) {
  const float* x       = (const float*)d_in[0];
  const float* w_conv  = (const float*)d_in[1];
  const float* b_conv  = (const float*)d_in[2];
  const float* w_score = (const float*)d_in[3];
  const float* b_score = (const float*)d_in[4];
  const float* w_loc   = (const float*)d_in[5];
  const float* b_loc   = (const float*)d_in[6];
  const int*   img_h   = (const int*)d_in[7];
  const int*   img_w   = (const int*)d_in[8];

  float* out        = (float*)d_out;
  float* out_locs   = out;                 // (4,36864,4)  589824
  float* out_scores = out + 589824;        // (4,36864,2)  294912
  float* out_rois   = out + 884736;        // (4,300,4)      4800
  float* out_ridx   = out + 889536;        // (4,300)        1200
  float* out_anchor = out + 890736;        // (1,36864,4)  147456

  // ws: feat2 33.55MB | region A: w4 9.44MB (dead after conv3) aliased by
  // boxes/keys/sboxes/sup (9.28MB) | hist 1MB + cut/cnt | cand 1.18MB
  float* feat2 = (float*)d_ws;                            // 8388608 f32
  float* A     = feat2 + (size_t)8388608;
  float* w4    = A;                                       // 2359296 f32
  float* boxes = A;                                       // 589824 f32
  unsigned* keys = (unsigned*)(boxes + 589824);           // 147456 u32
  float* sboxes  = (float*)(keys + 147456);               // 48000 f32
  unsigned long long* sup = (unsigned long long*)(sboxes + 48000); // 768000 u64
  unsigned* hist = (unsigned*)(A + 2359296);              // 262144 u32
  unsigned* cut  = hist + 262144;                         // 4 u32
  unsigned* cnt  = cut + 4;                               // 4 u32 (+pad)
  unsigned long long* cand = (unsigned long long*)(hist + 262144 + 16); // 147456 u64

  hipMemsetAsync(hist, 0, 262144 * 4 + 64, stream);       // hist + cut + cnt
  reshape_w_kernel<<<9216, 256, 0, stream>>>(w_conv, w4);
  conv3_kernel<<<dim3(16, 16, 4), 256, 0, stream>>>(x, w4, b_conv, feat2);
  conv1_kernel<<<dim3(64, 4), 256, 0, stream>>>(feat2, w_loc, b_loc,
                                                w_score, b_score, out_locs, out_scores);
  decode_kernel<<<576, 256, 0, stream>>>(out_locs, out_scores, img_h, img_w,
                                         boxes, keys, hist, out_anchor);
  scan_kernel<<<4, 256, 0, stream>>>(hist, cut);
  compact_kernel<<<576, 256, 0, stream>>>(keys, cut, cnt, cand);
  rank2_kernel<<<dim3(144, 4), 256, 0, stream>>>(cand, cnt, boxes, sboxes);
  iou_kernel<<<dim3(PREN, 4), 256, 0, stream>>>(sboxes, sup);
  nms_kernel<<<4, 64, 0, stream>>>(sup, sboxes, out_rois, out_ridx);
}